// Round 2
// 17785.892 us; speedup vs baseline: 1.0495x; 1.0495x over previous
//
#include <hip/hip_runtime.h>
#include <hip/hip_bf16.h>
#include <math.h>

#define BB 256     // batch
#define TT 128     // timesteps
#define HH 256     // hidden
#define NBR 16     // batch rows per workgroup
#define BLK 1024   // threads per block (16 waves)

typedef short bf8 __attribute__((ext_vector_type(8)));   // 8 bf16 (4 VGPRs)
typedef float f4  __attribute__((ext_vector_type(4)));   // MFMA accumulator
#define MFMA16 __builtin_amdgcn_mfma_f32_16x16x32_bf16

// ---- workspace layout (PROVEN 41.2MB layout — do not grow) ----
constexpr size_t U_WC0  = 0;                                  // (2,1024,384) gate cat l0
constexpr size_t U_WC1  = U_WC0 + (size_t)2*1024*384;         // (2,1024,768) gate cat l1
constexpr size_t U_INP  = U_WC1 + (size_t)2*1024*768;         // (1024,256)
constexpr size_t U_XP   = U_INP + (size_t)1024*256;           // (48,512)
constexpr size_t U_OUTP = U_XP  + (size_t)48*512;             // (256,512)
constexpr size_t U_L0   = U_OUTP + (size_t)256*512;           // (B,T,512) l0 output bf16
constexpr size_t U_END  = U_L0 + (size_t)BB*TT*512;
constexpr size_t FOFF   = U_END * 2;                          // byte offset of f32 region
constexpr size_t F_BSUM0 = 0;                 // (2,1024)
constexpr size_t F_BSUM1 = F_BSUM0 + 2048;    // (2,1024)
constexpr size_t F_H0    = F_BSUM1 + 2048;    // (2,B,256)
constexpr size_t F_C0    = F_H0 + 2*BB*256;
constexpr size_t F_H1    = F_C0 + 2*BB*256;
constexpr size_t F_C1    = F_H1 + 2*BB*256;

__device__ __forceinline__ short f2bs(float v) {
    __hip_bfloat16 b = __float2bfloat16(v);
    short s; __builtin_memcpy(&s, &b, 2); return s;
}
__device__ __forceinline__ float bs2f(short s) {
    unsigned int u = ((unsigned int)(unsigned short)s) << 16;
    float f; __builtin_memcpy(&f, &u, 4); return f;
}
__device__ __forceinline__ float sigmoidf_(float x) { return 1.0f / (1.0f + __expf(-x)); }
__device__ __forceinline__ float tanhf_(float x) {
    float e = __expf(-2.0f * fabsf(x));
    float t = (1.0f - e) / (1.0f + e);
    return copysignf(t, x);
}
__device__ __forceinline__ float softplusf_(float x) {
    return log1pf(__expf(-fabsf(x))) + fmaxf(x, 0.0f);
}
__device__ __forceinline__ float loadval(const float* p) { return *p; }
__device__ __forceinline__ float loadval(const short* p) { return bs2f(*p); }
__device__ __forceinline__ void storeval(float* p, float v) { *p = v; }
__device__ __forceinline__ void storeval(short* p, float v) { *p = f2bs(v); }

// ---------------- prep: convert weights f32->bf16 (original [n][k] layout), cat gates, bsum, zero states ----
__global__ __launch_bounds__(256)
void prep2(const float* __restrict__ w_ih_l0, const float* __restrict__ w_hh_l0,
           const float* __restrict__ b_ih_l0, const float* __restrict__ b_hh_l0,
           const float* __restrict__ w_ih_l1, const float* __restrict__ w_hh_l1,
           const float* __restrict__ b_ih_l1, const float* __restrict__ b_hh_l1,
           const float* __restrict__ in_proj_w, const float* __restrict__ x_proj_w,
           const float* __restrict__ out_proj_w,
           short* __restrict__ wsu, float* __restrict__ wsf)
{
    const int nt = gridDim.x * blockDim.x;
    const int g0 = blockIdx.x * blockDim.x + threadIdx.x;

    for (int idx = g0; idx < 2*1024*384; idx += nt) {
        int dir = idx / (1024*384), rem = idx % (1024*384);
        int n = rem / 384, k = rem % 384;
        float v = (k < 128) ? w_ih_l0[(size_t)dir*1024*128 + (size_t)n*128 + k]
                            : w_hh_l0[(size_t)dir*1024*256 + (size_t)n*256 + (k-128)];
        wsu[U_WC0 + idx] = f2bs(v);
    }
    for (int idx = g0; idx < 2*1024*768; idx += nt) {
        int dir = idx / (1024*768), rem = idx % (1024*768);
        int n = rem / 768, k = rem % 768;
        float v = (k < 512) ? w_ih_l1[(size_t)dir*1024*512 + (size_t)n*512 + k]
                            : w_hh_l1[(size_t)dir*1024*256 + (size_t)n*256 + (k-512)];
        wsu[U_WC1 + idx] = f2bs(v);
    }
    for (int idx = g0; idx < 1024*256; idx += nt) wsu[U_INP  + idx] = f2bs(in_proj_w[idx]);
    for (int idx = g0; idx < 48*512;   idx += nt) wsu[U_XP   + idx] = f2bs(x_proj_w[idx]);
    for (int idx = g0; idx < 256*512;  idx += nt) wsu[U_OUTP + idx] = f2bs(out_proj_w[idx]);
    for (int idx = g0; idx < 2048; idx += nt) {
        wsf[F_BSUM0 + idx] = b_ih_l0[idx] + b_hh_l0[idx];
        wsf[F_BSUM1 + idx] = b_ih_l1[idx] + b_hh_l1[idx];
    }
    for (int idx = g0; idx < 2*BB*256; idx += nt) {
        wsf[F_H0 + idx] = 0.0f;
        wsf[F_C0 + idx] = 0.0f;
    }
}

// ---------------- MFMA layer kernel: one WG = 16 batch rows of one direction, 16 waves ----------------
// 16 waves (4/SIMD) double memory-level parallelism vs the 8-wave version: same 32 WGs,
// same weight bytes/step, ~2x outstanding L2 loads per CU -> latency-stall ~halved (theory).
template<int DIN, typename TIn, typename TOut>
__global__ __launch_bounds__(BLK, 4)
void layer_mfma(const TIn* __restrict__ in,        // (B,T,DIN)
                TOut* __restrict__ out,             // (B,T,512): this dir writes [dir*256, +256)
                const short* __restrict__ Wcat,     // (2,1024,KG) bf16 [dir][n][k]
                const short* __restrict__ Winp,     // (1024,256)
                const short* __restrict__ Wxp,      // (48,512)
                const short* __restrict__ Woutp,    // (256,512)
                const float* __restrict__ bsum_all, // (2,1024)
                const float* __restrict__ conv_w,   // (512,2) f32
                const float* __restrict__ conv_b,   // (512)
                const float* __restrict__ dtw,      // (512,16) f32
                const float* __restrict__ dtb,      // (512)
                const float* __restrict__ Dm,       // (512)
                const float* __restrict__ h_init, const float* __restrict__ c_init,  // (2,B,256)
                float* __restrict__ h_fin, float* __restrict__ c_fin)
{
    constexpr int KG = DIN + 256;          // gate GEMM K (u|h concatenated)
    const int tid = threadIdx.x;
    const int wv = tid >> 6, ln = tid & 63;
    const int lr = ln & 15, lq = ln >> 4;  // lane row/col-in-tile, k-quad
    // dir-per-XCD clustering: blocks round-robin XCDs by blockIdx.x%8; XCD 0-3 dir0, 4-7 dir1.
    // halves the per-XCD L2 weight footprint (perf heuristic only; any mapping is correct).
    const int raw = blockIdx.x;
    const int xcd = raw & 7, slot = raw >> 3;
    const int dir = xcd >> 2;
    const int b0 = (slot * 4 + (xcd & 3)) * NBR;

    const short* Wg = Wcat + (size_t)dir * 1024 * KG;

    __shared__ __attribute__((aligned(16))) short sA[16*776];    // [u(0..DIN) | h(DIN..DIN+256)]
    __shared__ __attribute__((aligned(16))) short sUm[16*264];   // mamba input bf16
    __shared__ __attribute__((aligned(16))) short sXm[16*520];   // xm, later y (in-place)
    __shared__ __attribute__((aligned(16))) short sZs[16*520];   // silu(z)
    __shared__ float sG[16*265], sO[16*265];                     // g/o gates f32
    __shared__ float sXd[16*52];                                 // x_dbl f32
    __shared__ float sC[16*257];                                 // cell state f32 (f-gate pre-folded)
    __shared__ float sBsum[1024];

    for (int idx = tid; idx < 1024; idx += BLK) sBsum[idx] = bsum_all[dir*1024 + idx];
    for (int idx = tid; idx < 16*256; idx += BLK) {
        int r = idx >> 8, k = idx & 255;
        size_t src = ((size_t)dir*BB + b0 + r)*256 + k;
        sA[r*776 + DIN + k] = f2bs(h_init[src]);
        sC[r*257 + k] = c_init[src];
    }
    // hoisted per-thread constants (were global re-reads every timestep)
    const int pd = tid & 511;
    float w16[16];
    #pragma unroll
    for (int p = 0; p < 16; ++p) w16[p] = dtw[pd*16 + p];
    const float dtbv = dtb[pd], Dmv = Dm[pd];
    float cwv[4], cbv[4];
    if (wv < 8) {
        #pragma unroll
        for (int i = 0; i < 4; ++i) {
            int col = wv*64 + i*16 + lr;
            cwv[i] = conv_w[col*2 + 1];
            cbv[i] = conv_b[col];
        }
    }
    __syncthreads();

    for (int t = 0; t < TT; ++t) {
        const int t_in = dir ? (TT - 1 - t) : t;

        // ---- load u into A_cat[.,0..DIN) ----
        for (int idx = tid; idx < 16*DIN; idx += BLK) {
            int r = idx / DIN, d = idx % DIN;
            sA[r*776 + d] = f2bs(loadval(&in[((size_t)(b0 + r)*TT + t_in)*DIN + d]));
        }
        __syncthreads();

        // ---- GEMM1: gates[16x1024] = [u|h] @ Wcat^T, K=KG; 16 waves x 4 n-tiles ----
        {
            f4 acc[4];
            #pragma unroll
            for (int i = 0; i < 4; ++i) acc[i] = (f4){0.f,0.f,0.f,0.f};
            const int arow = lr*776 + lq*8;
            #pragma unroll 2
            for (int k0 = 0; k0 < KG; k0 += 32) {
                bf8 a = *(const bf8*)&sA[arow + k0];
                #pragma unroll
                for (int i = 0; i < 4; ++i) {
                    int n = wv*64 + i*16 + lr;
                    bf8 b = *(const bf8*)&Wg[(size_t)n*KG + k0 + lq*8];
                    acc[i] = MFMA16(a, b, acc[i], 0, 0, 0);
                }
            }
            if (wv < 4) {
                // cols 0..255: raw mamba input (no bias)
                #pragma unroll
                for (int i = 0; i < 4; ++i) {
                    int col = wv*64 + i*16 + lr;
                    #pragma unroll
                    for (int j = 0; j < 4; ++j)
                        sUm[(lq*4+j)*264 + col] = f2bs(acc[i][j]);
                }
            } else if (wv < 8) {
                // f gate: fold directly into cell state
                #pragma unroll
                for (int i = 0; i < 4; ++i) {
                    int col = wv*64 + i*16 + lr;
                    int k = col - 256;
                    float bsv = sBsum[col];
                    #pragma unroll
                    for (int j = 0; j < 4; ++j) {
                        float f_t = sigmoidf_(acc[i][j] + bsv);
                        sC[(lq*4+j)*257 + k] *= f_t;
                    }
                }
            } else if (wv < 12) {
                #pragma unroll
                for (int i = 0; i < 4; ++i) {
                    int col = wv*64 + i*16 + lr;
                    int kk = col & 255;
                    float bsv = sBsum[col];
                    #pragma unroll
                    for (int j = 0; j < 4; ++j)
                        sG[(lq*4+j)*265 + kk] = tanhf_(acc[i][j] + bsv);
                }
            } else {
                #pragma unroll
                for (int i = 0; i < 4; ++i) {
                    int col = wv*64 + i*16 + lr;
                    int kk = col & 255;
                    float bsv = sBsum[col];
                    #pragma unroll
                    for (int j = 0; j < 4; ++j)
                        sO[(lq*4+j)*265 + kk] = sigmoidf_(acc[i][j] + bsv);
                }
            }
        }
        __syncthreads();

        // ---- GEMM2: xz[16x1024] = um @ Winp^T, K=256; fuse conv+silu ----
        {
            f4 acc[4];
            #pragma unroll
            for (int i = 0; i < 4; ++i) acc[i] = (f4){0.f,0.f,0.f,0.f};
            const int arow = lr*264 + lq*8;
            #pragma unroll 2
            for (int k0 = 0; k0 < 256; k0 += 32) {
                bf8 a = *(const bf8*)&sUm[arow + k0];
                #pragma unroll
                for (int i = 0; i < 4; ++i) {
                    int n = wv*64 + i*16 + lr;
                    bf8 b = *(const bf8*)&Winp[(size_t)n*256 + k0 + lq*8];
                    acc[i] = MFMA16(a, b, acc[i], 0, 0, 0);
                }
            }
            if (wv < 8) {
                #pragma unroll
                for (int i = 0; i < 4; ++i) {
                    int col = wv*64 + i*16 + lr;
                    #pragma unroll
                    for (int j = 0; j < 4; ++j) {
                        float v = fmaf(acc[i][j], cwv[i], cbv[i]);
                        sXm[(lq*4+j)*520 + col] = f2bs(v * sigmoidf_(v));
                    }
                }
            } else {
                #pragma unroll
                for (int i = 0; i < 4; ++i) {
                    int cz = wv*64 + i*16 + lr - 512;
                    #pragma unroll
                    for (int j = 0; j < 4; ++j) {
                        float z = acc[i][j];
                        sZs[(lq*4+j)*520 + cz] = f2bs(z * sigmoidf_(z));
                    }
                }
            }
        }
        __syncthreads();

        // ---- GEMM3: x_dbl[16x48] = xm @ Wxp^T, K=512 (waves 0..2) ----
        if (wv < 3) {
            f4 acc = (f4){0.f,0.f,0.f,0.f};
            const int arow = lr*520 + lq*8;
            #pragma unroll 2
            for (int k0 = 0; k0 < 512; k0 += 32) {
                bf8 a = *(const bf8*)&sXm[arow + k0];
                bf8 b = *(const bf8*)&Wxp[(size_t)(wv*16 + lr)*512 + k0 + lq*8];
                acc = MFMA16(a, b, acc, 0, 0, 0);
            }
            #pragma unroll
            for (int j = 0; j < 4; ++j)
                sXd[(lq*4+j)*52 + wv*16 + lr] = acc[j];
        }
        __syncthreads();

        // ---- phase4: delta/bc/y elementwise; two 512-thread halves x 8 rows each ----
        {
            const int d = pd;
            const int r0 = (tid >> 9) * 8;
            for (int r = r0; r < r0 + 8; ++r) {
                float dp = dtbv;
                #pragma unroll
                for (int p = 0; p < 16; ++p) dp = fmaf(sXd[r*52 + p], w16[p], dp);
                float bc = 0.f;
                #pragma unroll
                for (int s = 0; s < 16; ++s) bc = fmaf(sXd[r*52 + 16 + s], sXd[r*52 + 32 + s], bc);
                float xmv = bs2f(sXm[r*520 + d]);
                float zsv = bs2f(sZs[r*520 + d]);
                float yv = fmaf(softplusf_(dp), bc, Dmv) * xmv * zsv;
                sXm[r*520 + d] = f2bs(yv);
            }
        }
        __syncthreads();

        // ---- GEMM4: mo[16x256] = y @ Woutp^T, K=512; 16 waves x 1 n-tile; fuse gate combine ----
        {
            f4 acc = (f4){0.f,0.f,0.f,0.f};
            const int arow = lr*520 + lq*8;
            const int n = wv*16 + lr;
            #pragma unroll 2
            for (int k0 = 0; k0 < 512; k0 += 32) {
                bf8 a = *(const bf8*)&sXm[arow + k0];
                bf8 b = *(const bf8*)&Woutp[(size_t)n*512 + k0 + lq*8];
                acc = MFMA16(a, b, acc, 0, 0, 0);
            }
            const int k = n;
            const float bsv = sBsum[k];
            #pragma unroll
            for (int j = 0; j < 4; ++j) {
                int r = lq*4 + j;
                float i_t = sigmoidf_(acc[j] + bsv);
                float g_t = sG[r*265 + k];
                float o_t = sO[r*265 + k];
                float cv = sC[r*257 + k] + i_t * g_t;   // f*c pre-folded in G1
                sC[r*257 + k] = cv;
                float hv = o_t * tanhf_(cv);
                sA[r*776 + DIN + k] = f2bs(hv);
                storeval(&out[((size_t)(b0 + r)*TT + t_in)*512 + (size_t)dir*256 + k], hv);
            }
        }
        // no trailing sync: next u-load writes a disjoint LDS region; its syncthreads
        // orders all combine writes before GEMM1 reads.
    }

    __syncthreads();
    for (int idx = tid; idx < 16*256; idx += BLK) {
        int r = idx >> 8, k = idx & 255;
        size_t dst = ((size_t)dir*BB + b0 + r)*256 + k;
        h_fin[dst] = bs2f(sA[r*776 + DIN + k]);
        c_fin[dst] = sC[r*257 + k];
    }
}

extern "C" void kernel_launch(void* const* d_in, const int* in_sizes, int n_in,
                              void* d_out, int out_size, void* d_ws, size_t ws_size,
                              hipStream_t stream)
{
    const float* x          = (const float*)d_in[0];
    const float* w_ih_l0    = (const float*)d_in[1];
    const float* w_hh_l0    = (const float*)d_in[2];
    const float* b_ih_l0    = (const float*)d_in[3];
    const float* b_hh_l0    = (const float*)d_in[4];
    const float* w_ih_l1    = (const float*)d_in[5];
    const float* w_hh_l1    = (const float*)d_in[6];
    const float* b_ih_l1    = (const float*)d_in[7];
    const float* b_hh_l1    = (const float*)d_in[8];
    const float* in_proj_w  = (const float*)d_in[9];
    const float* conv_w     = (const float*)d_in[10];
    const float* conv_b     = (const float*)d_in[11];
    const float* x_proj_w   = (const float*)d_in[12];
    const float* dt_proj_w  = (const float*)d_in[13];
    const float* dt_proj_b  = (const float*)d_in[14];
    const float* D_m        = (const float*)d_in[15];
    const float* out_proj_w = (const float*)d_in[16];

    short* wsu = (short*)d_ws;
    float* wsf = (float*)((char*)d_ws + FOFF);

    prep2<<<512, 256, 0, stream>>>(
        w_ih_l0, w_hh_l0, b_ih_l0, b_hh_l0,
        w_ih_l1, w_hh_l1, b_ih_l1, b_hh_l1,
        in_proj_w, x_proj_w, out_proj_w, wsu, wsf);

    // layer 0: x fp32 (DIN=128) -> l0out bf16; zero init states; finals -> H1/C1
    layer_mfma<128, float, short><<<32, BLK, 0, stream>>>(
        x, wsu + U_L0,
        wsu + U_WC0, wsu + U_INP, wsu + U_XP, wsu + U_OUTP,
        wsf + F_BSUM0, conv_w, conv_b, dt_proj_w, dt_proj_b, D_m,
        wsf + F_H0, wsf + F_C0, wsf + F_H1, wsf + F_C1);

    // layer 1: l0out bf16 (DIN=512) -> d_out fp32; init from H1/C1
    layer_mfma<512, short, float><<<32, BLK, 0, stream>>>(
        wsu + U_L0, (float*)d_out,
        wsu + U_WC1, wsu + U_INP, wsu + U_XP, wsu + U_OUTP,
        wsf + F_BSUM1, conv_w, conv_b, dt_proj_w, dt_proj_b, D_m,
        wsf + F_H1, wsf + F_C1, wsf + F_H0, wsf + F_C0);
}

// Round 3
// 12636.874 us; speedup vs baseline: 1.4772x; 1.4075x over previous
//
#include <hip/hip_runtime.h>
#include <hip/hip_bf16.h>
#include <math.h>

#define BB 256     // batch
#define TT 128     // timesteps
#define NBR 16     // batch rows per group
#define BLK 512    // threads per block (8 waves)

typedef short bf8 __attribute__((ext_vector_type(8)));   // 8 bf16 (4 VGPRs)
typedef float f4  __attribute__((ext_vector_type(4)));   // MFMA accumulator
#define MFMA16 __builtin_amdgcn_mfma_f32_16x16x32_bf16

// ---- workspace layout: proven 41.2MB layout + 4.3MB comm region ----
constexpr size_t U_WC0  = 0;                                  // (2,1024,384) gate cat l0
constexpr size_t U_WC1  = U_WC0 + (size_t)2*1024*384;         // (2,1024,768) gate cat l1
constexpr size_t U_INP  = U_WC1 + (size_t)2*1024*768;         // (1024,256)
constexpr size_t U_XP   = U_INP + (size_t)1024*256;           // (48,512)
constexpr size_t U_OUTP = U_XP  + (size_t)48*512;             // (256,512)
constexpr size_t U_L0   = U_OUTP + (size_t)256*512;           // (B,T,512) l0 output bf16
constexpr size_t U_END  = U_L0 + (size_t)BB*TT*512;
constexpr size_t FOFF   = U_END * 2;                          // byte offset of f32 region
constexpr size_t F_BSUM0 = 0;                 // (2,1024)
constexpr size_t F_BSUM1 = F_BSUM0 + 2048;    // (2,1024)
constexpr size_t F_H0    = F_BSUM1 + 2048;    // (2,B,256)
constexpr size_t F_C0    = F_H0 + 2*BB*256;
constexpr size_t F_H1    = F_C0 + 2*BB*256;
constexpr size_t F_C1    = F_H1 + 2*BB*256;
constexpr size_t F_CNT   = F_C1 + 2*BB*256;   // 64 u32 sync counters (2 layers x 32 groups)
constexpr size_t F_COMM  = F_CNT + 64;
// per-group comm block (4-byte words):
constexpr int C_UM  = 0;        // 16x256 f32  raw mamba input (G1 cols 0..255)
constexpr int C_F   = 4096;     // 16x256 f32  sigmoid(f) (G1 cols 256..511)
constexpr int C_G   = 8192;     // 16x256 f32  tanh(g)
constexpr int C_O   = 12288;    // 16x256 f32  sigmoid(o)
constexpr int C_XM  = 16384;    // 16x256 u32  bf16-pair xm cols 0..511
constexpr int C_ZS  = 20480;    // 16x256 u32  bf16-pair silu(z)
constexpr int C_XDP = 24576;    // 4 x 16x48 f32 xd K-partials
constexpr int C_Y   = 27648;    // 16x256 u32  bf16-pair y
constexpr int C_H   = 31744;    // 16x128 u32  bf16-pair h
constexpr int GSTR  = 33792;    // group stride (132KB); x32 groups = 4.2MB

__device__ __forceinline__ short f2bs(float v) {
    __hip_bfloat16 b = __float2bfloat16(v);
    short s; __builtin_memcpy(&s, &b, 2); return s;
}
__device__ __forceinline__ float bs2f(short s) {
    unsigned int u = ((unsigned int)(unsigned short)s) << 16;
    float f; __builtin_memcpy(&f, &u, 4); return f;
}
__device__ __forceinline__ float sigmoidf_(float x) { return 1.0f / (1.0f + __expf(-x)); }
__device__ __forceinline__ float tanhf_(float x) {
    float e = __expf(-2.0f * fabsf(x));
    float t = (1.0f - e) / (1.0f + e);
    return copysignf(t, x);
}
__device__ __forceinline__ float softplusf_(float x) {
    return log1pf(__expf(-fabsf(x))) + fmaxf(x, 0.0f);
}
__device__ __forceinline__ float loadval(const float* p) { return *p; }
__device__ __forceinline__ float loadval(const short* p) { return bs2f(*p); }
__device__ __forceinline__ void storeval(float* p, float v) { *p = v; }
__device__ __forceinline__ void storeval(short* p, float v) { *p = f2bs(v); }

// device-scope (cross-XCD-coherent) comm accessors: sc0 loads/stores, no L2 invalidates
__device__ __forceinline__ void a_st(float* p, float v) {
    __hip_atomic_store(p, v, __ATOMIC_RELAXED, __HIP_MEMORY_SCOPE_AGENT);
}
__device__ __forceinline__ float a_ldf(float* p) {
    return __hip_atomic_load(p, __ATOMIC_RELAXED, __HIP_MEMORY_SCOPE_AGENT);
}
__device__ __forceinline__ void a_stu(unsigned* p, unsigned v) {
    __hip_atomic_store(p, v, __ATOMIC_RELAXED, __HIP_MEMORY_SCOPE_AGENT);
}
__device__ __forceinline__ unsigned a_ldu(unsigned* p) {
    return __hip_atomic_load(p, __ATOMIC_RELAXED, __HIP_MEMORY_SCOPE_AGENT);
}

// group flag-sync: monotonic counter; release-add, relaxed spin (thread 0 only)
__device__ __forceinline__ void gsync(unsigned* cnt, unsigned target) {
    __syncthreads();   // all waves drain their (sc0) stores before arrival
    if (threadIdx.x == 0) {
        __hip_atomic_fetch_add(cnt, 1u, __ATOMIC_RELEASE, __HIP_MEMORY_SCOPE_AGENT);
        while (__hip_atomic_load(cnt, __ATOMIC_RELAXED, __HIP_MEMORY_SCOPE_AGENT) < target)
            __builtin_amdgcn_s_sleep(2);
    }
    __syncthreads();
    asm volatile("" ::: "memory");   // compiler-only fence; HW side safe via sc0 accesses
}

// ---------------- prep: convert weights f32->bf16, cat gates, bsum, zero states+counters ----
__global__ __launch_bounds__(256)
void prep2(const float* __restrict__ w_ih_l0, const float* __restrict__ w_hh_l0,
           const float* __restrict__ b_ih_l0, const float* __restrict__ b_hh_l0,
           const float* __restrict__ w_ih_l1, const float* __restrict__ w_hh_l1,
           const float* __restrict__ b_ih_l1, const float* __restrict__ b_hh_l1,
           const float* __restrict__ in_proj_w, const float* __restrict__ x_proj_w,
           const float* __restrict__ out_proj_w,
           short* __restrict__ wsu, float* __restrict__ wsf)
{
    const int nt = gridDim.x * blockDim.x;
    const int g0 = blockIdx.x * blockDim.x + threadIdx.x;

    for (int idx = g0; idx < 2*1024*384; idx += nt) {
        int dir = idx / (1024*384), rem = idx % (1024*384);
        int n = rem / 384, k = rem % 384;
        float v = (k < 128) ? w_ih_l0[(size_t)dir*1024*128 + (size_t)n*128 + k]
                            : w_hh_l0[(size_t)dir*1024*256 + (size_t)n*256 + (k-128)];
        wsu[U_WC0 + idx] = f2bs(v);
    }
    for (int idx = g0; idx < 2*1024*768; idx += nt) {
        int dir = idx / (1024*768), rem = idx % (1024*768);
        int n = rem / 768, k = rem % 768;
        float v = (k < 512) ? w_ih_l1[(size_t)dir*1024*512 + (size_t)n*512 + k]
                            : w_hh_l1[(size_t)dir*1024*256 + (size_t)n*256 + (k-512)];
        wsu[U_WC1 + idx] = f2bs(v);
    }
    for (int idx = g0; idx < 1024*256; idx += nt) wsu[U_INP  + idx] = f2bs(in_proj_w[idx]);
    for (int idx = g0; idx < 48*512;   idx += nt) wsu[U_XP   + idx] = f2bs(x_proj_w[idx]);
    for (int idx = g0; idx < 256*512;  idx += nt) wsu[U_OUTP + idx] = f2bs(out_proj_w[idx]);
    for (int idx = g0; idx < 2048; idx += nt) {
        wsf[F_BSUM0 + idx] = b_ih_l0[idx] + b_hh_l0[idx];
        wsf[F_BSUM1 + idx] = b_ih_l1[idx] + b_hh_l1[idx];
    }
    for (int idx = g0; idx < 2*BB*256; idx += nt) {
        wsf[F_H0 + idx] = 0.0f;
        wsf[F_C0 + idx] = 0.0f;
    }
    unsigned* cnt = (unsigned*)(wsf + F_CNT);
    for (int idx = g0; idx < 64; idx += nt) cnt[idx] = 0;
}

// ---------------- cooperative layer kernel ----------------
// 256 WGs = 32 groups x 8 members. Group = (dir, 16 batch rows); member j owns a
// 128-col slice of G1/G2, K-slice of G3, 32-col slice of G4 + h/c update.
// Per-WG weight stream: ~300KB/step (was 2.3MB) -> the per-CU pull-rate wall
// (r0-r2 evidence: ~29GB/s/CU regardless of waves/source) is split over 8 CUs.
template<int DIN, typename TIn, typename TOut>
__global__ __launch_bounds__(BLK)
void layer_coop(const TIn* __restrict__ in,        // (B,T,DIN)
                TOut* __restrict__ out,             // (B,T,512): dir writes [dir*256,+256)
                const short* __restrict__ Wcat,     // (2,1024,KG) bf16
                const short* __restrict__ Winp,     // (1024,256)
                const short* __restrict__ Wxp,      // (48,512)
                const short* __restrict__ Woutp,    // (256,512)
                const float* __restrict__ bsum_all, // (2,1024)
                const float* __restrict__ conv_w,   // (512,2)
                const float* __restrict__ conv_b,   // (512)
                const float* __restrict__ dtw,      // (512,16)
                const float* __restrict__ dtb,      // (512)
                const float* __restrict__ Dm,       // (512)
                const float* __restrict__ h_init, const float* __restrict__ c_init,
                float* __restrict__ h_fin, float* __restrict__ c_fin,
                float* commAll, unsigned* cntAll, int layer)
{
    constexpr int KG = DIN + 256;
    const int tid = threadIdx.x;
    const int wv = tid >> 6, ln = tid & 63;
    const int lr = ln & 15, lq = ln >> 4;
    // same-XCD group packing (perf heuristic; correctness is placement-independent)
    const int bid = blockIdx.x;
    const int xcd = bid & 7, slot = bid >> 3;      // 32 slots per XCD
    const int g = xcd * 4 + (slot >> 3);           // group 0..31 (4 groups per XCD)
    const int j = slot & 7;                        // member 0..7
    const int dir = g >> 4;
    const int b0 = (g & 15) * NBR;

    float* comm = commAll + (size_t)g * GSTR;
    unsigned* comm_u = (unsigned*)comm;
    unsigned* cnt = cntAll + layer * 32 + g;

    const short* Wg = Wcat + (size_t)dir * 1024 * KG;

    __shared__ __attribute__((aligned(16))) short sA[16*776];    // [u(0..DIN) | h(DIN..+256)]
    __shared__ __attribute__((aligned(16))) short sUm[16*264];   // full um bf16
    __shared__ __attribute__((aligned(16))) short sLoc[16*132];  // own xm-or-zs slice bf16
    __shared__ __attribute__((aligned(16))) short sY[16*524];    // full y bf16
    __shared__ short sXmP[16*68], sZsP[16*68], sYloc[16*68], sHloc[16*36];
    __shared__ float sXd[16*52], sFs[16*36], sGs[16*36], sOs[16*36], sC[16*36];

    // ---- init ----
    for (int idx = tid; idx < 16*256; idx += BLK) {
        int r = idx >> 8, k = idx & 255;
        sA[r*776 + DIN + k] = f2bs(h_init[((size_t)dir*BB + b0 + r)*256 + k]);
    }
    for (int idx = tid; idx < 16*32; idx += BLK) {
        int r = idx >> 5, kk = idx & 31;
        sC[r*36 + kk] = c_init[((size_t)dir*BB + b0 + r)*256 + 32*j + kk];
    }
    // hoisted per-lane constants
    const int nloc = wv*16 + lr;                 // 0..127
    const int c1 = 128*j + nloc;                 // this lane's G1/G2 column
    const float bs1 = bsum_all[dir*1024 + c1];
    float cw = 0.f, cb = 0.f;
    if (j < 4) { cw = conv_w[c1*2 + 1]; cb = conv_b[c1]; }
    const int col4 = 32*j + nloc;                // valid for wv<2
    const float bs4 = (wv < 2) ? bsum_all[dir*1024 + col4] : 0.f;
    const int d = 64*j + (tid & 63), dloc = tid & 63, rb = tid >> 6;
    float w16[16];
    #pragma unroll
    for (int p = 0; p < 16; ++p) w16[p] = dtw[d*16 + p];
    const float dtbv = dtb[d], Dmv = Dm[d];

    unsigned target = 8;

    for (int t = 0; t < TT; ++t) {
        const int t_in = dir ? (TT-1-t) : t;

        // ---- A: copy u (and h from comm for t>0) into sA ----
        for (int idx = tid; idx < 16*DIN; idx += BLK) {
            int r = idx / DIN, dd = idx % DIN;
            sA[r*776 + dd] = f2bs(loadval(&in[((size_t)(b0+r)*TT + t_in)*DIN + dd]));
        }
        if (t > 0) {
            for (int idx = tid; idx < 16*128; idx += BLK) {
                int r = idx >> 7, kk = idx & 127;
                unsigned u = a_ldu(&comm_u[C_H + idx]);
                sA[r*776 + DIN + 2*kk]     = (short)(u & 0xffff);
                sA[r*776 + DIN + 2*kk + 1] = (short)(u >> 16);
            }
        }
        __syncthreads();

        // ---- B: G1 slice — gates[16 x own 128 cols] = [u|h] @ Wcat^T ----
        {
            f4 acc = (f4){0.f,0.f,0.f,0.f};
            const int arow = lr*776 + lq*8;
            const short* brow = &Wg[(size_t)c1*KG + lq*8];
            #pragma unroll 4
            for (int k0 = 0; k0 < KG; k0 += 32) {
                bf8 a = *(const bf8*)&sA[arow + k0];
                bf8 b = *(const bf8*)&brow[k0];
                acc = MFMA16(a, b, acc, 0, 0, 0);
            }
            if (j < 2) {            // raw mamba input cols 0..255 (no bias)
                #pragma unroll
                for (int jj = 0; jj < 4; ++jj)
                    a_st(&comm[C_UM + (lq*4+jj)*256 + c1], acc[jj]);
            } else {                // activated gates
                float* dst = (j < 4) ? &comm[C_F] : (j < 6) ? &comm[C_G] : &comm[C_O];
                const int cc = c1 & 255;
                const bool ist = (j >= 4 && j < 6);
                #pragma unroll
                for (int jj = 0; jj < 4; ++jj) {
                    float v = acc[jj] + bs1;
                    a_st(&dst[(lq*4+jj)*256 + cc], ist ? tanhf_(v) : sigmoidf_(v));
                }
            }
        }
        gsync(cnt, target); target += 8;   // S1

        // ---- C: stage full um + own f/g/o slices ----
        for (int idx = tid; idx < 16*256; idx += BLK) {
            int r = idx >> 8, k = idx & 255;
            sUm[r*264 + k] = f2bs(a_ldf(&comm[C_UM + idx]));
        }
        for (int idx = tid; idx < 16*32; idx += BLK) {
            int r = idx >> 5, kk = idx & 31;
            sFs[r*36+kk] = a_ldf(&comm[C_F + r*256 + 32*j + kk]);
            sGs[r*36+kk] = a_ldf(&comm[C_G + r*256 + 32*j + kk]);
            sOs[r*36+kk] = a_ldf(&comm[C_O + r*256 + 32*j + kk]);
        }
        __syncthreads();

        // ---- D: G2 slice — xz[16 x own 128 cols] = um @ Winp^T; conv+silu / silu ----
        {
            f4 acc = (f4){0.f,0.f,0.f,0.f};
            const int arow = lr*264 + lq*8;
            const short* brow = &Winp[(size_t)c1*256 + lq*8];
            #pragma unroll 4
            for (int k0 = 0; k0 < 256; k0 += 32) {
                bf8 a = *(const bf8*)&sUm[arow + k0];
                bf8 b = *(const bf8*)&brow[k0];
                acc = MFMA16(a, b, acc, 0, 0, 0);
            }
            #pragma unroll
            for (int jj = 0; jj < 4; ++jj) {
                float v = acc[jj];
                if (j < 4) v = fmaf(v, cw, cb);     // conv for xm half
                v = v * sigmoidf_(v);               // silu both halves
                sLoc[(lq*4+jj)*132 + nloc] = f2bs(v);
            }
        }
        __syncthreads();

        // ---- E: publish xm/zs slice (packed bf16 pairs) ----
        for (int idx = tid; idx < 16*64; idx += BLK) {
            int r = idx >> 6, kk = idx & 63;
            unsigned lo = (unsigned short)sLoc[r*132 + 2*kk];
            unsigned hi = (unsigned short)sLoc[r*132 + 2*kk + 1];
            unsigned u = (hi << 16) | lo;
            if (j < 4) a_stu(&comm_u[C_XM + r*256 + 64*j + kk], u);
            else       a_stu(&comm_u[C_ZS + r*256 + 64*(j-4) + kk], u);
        }
        // ---- F: G3 K-partial (j<4 own 128 k's; waves 0..2 cover 48 cols) ----
        if (j < 4 && wv < 3) {
            f4 acc = (f4){0.f,0.f,0.f,0.f};
            const int arow = lr*132 + lq*8;
            const short* brow = &Wxp[(size_t)nloc*512 + 128*j + lq*8];   // nloc<48
            #pragma unroll 4
            for (int k0 = 0; k0 < 128; k0 += 32) {
                bf8 a = *(const bf8*)&sLoc[arow + k0];
                bf8 b = *(const bf8*)&brow[k0];
                acc = MFMA16(a, b, acc, 0, 0, 0);
            }
            #pragma unroll
            for (int jj = 0; jj < 4; ++jj)
                a_st(&comm[C_XDP + j*768 + (lq*4+jj)*48 + nloc], acc[jj]);
        }
        gsync(cnt, target); target += 8;   // S2

        // ---- G: phase4 — own 64 channels ----
        for (int idx = tid; idx < 768; idx += BLK) {
            float s = a_ldf(&comm[C_XDP + idx])        + a_ldf(&comm[C_XDP + 768 + idx])
                    + a_ldf(&comm[C_XDP + 1536 + idx]) + a_ldf(&comm[C_XDP + 2304 + idx]);
            int r = idx / 48, n = idx % 48;
            sXd[r*52 + n] = s;
        }
        for (int idx = tid; idx < 16*32; idx += BLK) {
            int r = idx >> 5, kk = idx & 31;
            unsigned ux = a_ldu(&comm_u[C_XM + r*256 + 32*j + kk]);
            sXmP[r*68 + 2*kk]   = (short)(ux & 0xffff);
            sXmP[r*68 + 2*kk+1] = (short)(ux >> 16);
            unsigned uz = a_ldu(&comm_u[C_ZS + r*256 + 32*j + kk]);
            sZsP[r*68 + 2*kk]   = (short)(uz & 0xffff);
            sZsP[r*68 + 2*kk+1] = (short)(uz >> 16);
        }
        __syncthreads();
        #pragma unroll
        for (int hh = 0; hh < 2; ++hh) {
            int r = rb + hh*8;
            float dp = dtbv;
            #pragma unroll
            for (int p = 0; p < 16; ++p) dp = fmaf(sXd[r*52 + p], w16[p], dp);
            float bc = 0.f;
            #pragma unroll
            for (int s = 0; s < 16; ++s) bc = fmaf(sXd[r*52+16+s], sXd[r*52+32+s], bc);
            float xmv = bs2f(sXmP[r*68 + dloc]);
            float zsv = bs2f(sZsP[r*68 + dloc]);
            float yv = fmaf(softplusf_(dp), bc, Dmv) * xmv * zsv;
            sYloc[r*68 + dloc] = f2bs(yv);
        }
        __syncthreads();
        // ---- H: publish y slice ----
        for (int idx = tid; idx < 16*32; idx += BLK) {
            int r = idx >> 5, kk = idx & 31;
            unsigned lo = (unsigned short)sYloc[r*68 + 2*kk];
            unsigned hi = (unsigned short)sYloc[r*68 + 2*kk+1];
            a_stu(&comm_u[C_Y + r*256 + 32*j + kk], (hi<<16)|lo);
        }
        gsync(cnt, target); target += 8;   // S3

        // ---- I: stage full y ----
        for (int idx = tid; idx < 16*256; idx += BLK) {
            int r = idx >> 8, kk = idx & 255;
            unsigned u = a_ldu(&comm_u[C_Y + idx]);
            sY[r*524 + 2*kk]   = (short)(u & 0xffff);
            sY[r*524 + 2*kk+1] = (short)(u >> 16);
        }
        __syncthreads();
        // ---- J: G4 slice — mo[16 x own 32 cols] = y @ Woutp^T; gate combine ----
        if (wv < 2) {
            f4 acc = (f4){0.f,0.f,0.f,0.f};
            const int arow = lr*524 + lq*8;
            const short* brow = &Woutp[(size_t)col4*512 + lq*8];
            #pragma unroll 4
            for (int k0 = 0; k0 < 512; k0 += 32) {
                bf8 a = *(const bf8*)&sY[arow + k0];
                bf8 b = *(const bf8*)&brow[k0];
                acc = MFMA16(a, b, acc, 0, 0, 0);
            }
            #pragma unroll
            for (int jj = 0; jj < 4; ++jj) {
                int r = lq*4 + jj;
                float i_t = sigmoidf_(acc[jj] + bs4);
                float cv = fmaf(sFs[r*36 + nloc], sC[r*36 + nloc], i_t * sGs[r*36 + nloc]);
                sC[r*36 + nloc] = cv;
                float hv = sOs[r*36 + nloc] * tanhf_(cv);
                sHloc[r*36 + nloc] = f2bs(hv);
                storeval(&out[((size_t)(b0+r)*TT + t_in)*512 + (size_t)dir*256 + col4], hv);
            }
        }
        __syncthreads();
        // ---- K: publish h slice ----
        for (int idx = tid; idx < 16*16; idx += BLK) {
            int r = idx >> 4, kk = idx & 15;
            unsigned lo = (unsigned short)sHloc[r*36 + 2*kk];
            unsigned hi = (unsigned short)sHloc[r*36 + 2*kk+1];
            a_stu(&comm_u[C_H + r*128 + 16*j + kk], (hi<<16)|lo);
        }
        gsync(cnt, target); target += 8;   // S4
    }

    // ---- finals: own 32-col slice ----
    for (int idx = tid; idx < 16*32; idx += BLK) {
        int r = idx >> 5, kk = idx & 31;
        size_t dst = ((size_t)dir*BB + b0 + r)*256 + 32*j + kk;
        h_fin[dst] = bs2f(sHloc[r*36 + kk]);
        c_fin[dst] = sC[r*36 + kk];
    }
}

extern "C" void kernel_launch(void* const* d_in, const int* in_sizes, int n_in,
                              void* d_out, int out_size, void* d_ws, size_t ws_size,
                              hipStream_t stream)
{
    const float* x          = (const float*)d_in[0];
    const float* w_ih_l0    = (const float*)d_in[1];
    const float* w_hh_l0    = (const float*)d_in[2];
    const float* b_ih_l0    = (const float*)d_in[3];
    const float* b_hh_l0    = (const float*)d_in[4];
    const float* w_ih_l1    = (const float*)d_in[5];
    const float* w_hh_l1    = (const float*)d_in[6];
    const float* b_ih_l1    = (const float*)d_in[7];
    const float* b_hh_l1    = (const float*)d_in[8];
    const float* in_proj_w  = (const float*)d_in[9];
    const float* conv_w     = (const float*)d_in[10];
    const float* conv_b     = (const float*)d_in[11];
    const float* x_proj_w   = (const float*)d_in[12];
    const float* dt_proj_w  = (const float*)d_in[13];
    const float* dt_proj_b  = (const float*)d_in[14];
    const float* D_m        = (const float*)d_in[15];
    const float* out_proj_w = (const float*)d_in[16];

    short* wsu = (short*)d_ws;
    float* wsf = (float*)((char*)d_ws + FOFF);
    float* commAll = wsf + F_COMM;
    unsigned* cntAll = (unsigned*)(wsf + F_CNT);

    prep2<<<512, 256, 0, stream>>>(
        w_ih_l0, w_hh_l0, b_ih_l0, b_hh_l0,
        w_ih_l1, w_hh_l1, b_ih_l1, b_hh_l1,
        in_proj_w, x_proj_w, out_proj_w, wsu, wsf);

    // layer 0: x fp32 (DIN=128) -> l0out bf16; finals -> H1/C1
    layer_coop<128, float, short><<<256, BLK, 0, stream>>>(
        x, wsu + U_L0,
        wsu + U_WC0, wsu + U_INP, wsu + U_XP, wsu + U_OUTP,
        wsf + F_BSUM0, conv_w, conv_b, dt_proj_w, dt_proj_b, D_m,
        wsf + F_H0, wsf + F_C0, wsf + F_H1, wsf + F_C1,
        commAll, cntAll, 0);

    // layer 1: l0out bf16 (DIN=512) -> d_out fp32; init from H1/C1
    layer_coop<512, short, float><<<256, BLK, 0, stream>>>(
        wsu + U_L0, (float*)d_out,
        wsu + U_WC1, wsu + U_INP, wsu + U_XP, wsu + U_OUTP,
        wsf + F_BSUM1, conv_w, conv_b, dt_proj_w, dt_proj_b, D_m,
        wsf + F_H1, wsf + F_C1, wsf + F_H0, wsf + F_C0,
        commAll, cntAll, 1);
}

// Round 4
// 10147.632 us; speedup vs baseline: 1.8395x; 1.2453x over previous
//
#include <hip/hip_runtime.h>
#include <hip/hip_bf16.h>
#include <math.h>

#define BB 256     // batch
#define TT 128     // timesteps
#define NBR 16     // batch rows per group
#define BLK 512    // threads per block (8 waves)

typedef short bf8 __attribute__((ext_vector_type(8)));   // 8 bf16 (4 VGPRs)
typedef float f4  __attribute__((ext_vector_type(4)));   // MFMA accumulator
#define MFMA16 __builtin_amdgcn_mfma_f32_16x16x32_bf16

// ---- workspace layout: proven 41.2MB layout + 1.6MB comm region ----
constexpr size_t U_WC0  = 0;                                  // (2,1024,384) gate cat l0
constexpr size_t U_WC1  = U_WC0 + (size_t)2*1024*384;         // (2,1024,768) gate cat l1
constexpr size_t U_INP  = U_WC1 + (size_t)2*1024*768;         // (1024,256)
constexpr size_t U_XP   = U_INP + (size_t)1024*256;           // (48,512)
constexpr size_t U_OUTP = U_XP  + (size_t)48*512;             // (256,512)
constexpr size_t U_L0   = U_OUTP + (size_t)256*512;           // (B,T,512) l0 output bf16
constexpr size_t U_END  = U_L0 + (size_t)BB*TT*512;
constexpr size_t FOFF   = U_END * 2;                          // byte offset of f32 region
constexpr size_t F_BSUM0 = 0;                 // (2,1024)
constexpr size_t F_BSUM1 = F_BSUM0 + 2048;    // (2,1024)
constexpr size_t F_H0    = F_BSUM1 + 2048;    // (2,B,256)
constexpr size_t F_C0    = F_H0 + 2*BB*256;
constexpr size_t F_H1    = F_C0 + 2*BB*256;
constexpr size_t F_C1    = F_H1 + 2*BB*256;
constexpr size_t F_CNT   = F_C1 + 2*BB*256;   // 64 u32 sync counters (2 layers x 32 groups)
constexpr size_t F_COMM  = F_CNT + 64;
// per-group comm block (u32 words, all packed bf16 pairs):
constexpr int C_UM  = 0;        // 16x128 u32  um (g[:, :256]) bf16 pairs
constexpr int C_XM  = 2048;     // 16x256 u32  xm bf16 pairs
constexpr int C_ZS  = 6144;     // 16x256 u32  silu(z) bf16 pairs
constexpr int C_H   = 10240;    // 16x128 u32  h bf16 pairs
constexpr int GSTR  = 12288;    // group stride (48KB); x32 groups = 1.5MB

__device__ __forceinline__ short f2bs(float v) {
    __hip_bfloat16 b = __float2bfloat16(v);
    short s; __builtin_memcpy(&s, &b, 2); return s;
}
__device__ __forceinline__ float bs2f(short s) {
    unsigned int u = ((unsigned int)(unsigned short)s) << 16;
    float f; __builtin_memcpy(&f, &u, 4); return f;
}
__device__ __forceinline__ float sigmoidf_(float x) { return 1.0f / (1.0f + __expf(-x)); }
__device__ __forceinline__ float tanhf_(float x) {
    float e = __expf(-2.0f * fabsf(x));
    float t = (1.0f - e) / (1.0f + e);
    return copysignf(t, x);
}
__device__ __forceinline__ float softplusf_(float x) {
    return log1pf(__expf(-fabsf(x))) + fmaxf(x, 0.0f);
}
__device__ __forceinline__ short conv2bs(float v) { return f2bs(v); }
__device__ __forceinline__ short conv2bs(short v) { return v; }
__device__ __forceinline__ void storeval(float* p, float v) { *p = v; }
__device__ __forceinline__ void storeval(short* p, float v) { *p = f2bs(v); }

// device-scope (cross-XCD-coherent) comm accessors
__device__ __forceinline__ void a_stu(unsigned* p, unsigned v) {
    __hip_atomic_store(p, v, __ATOMIC_RELAXED, __HIP_MEMORY_SCOPE_AGENT);
}
__device__ __forceinline__ unsigned a_ldu(unsigned* p) {
    return __hip_atomic_load(p, __ATOMIC_RELAXED, __HIP_MEMORY_SCOPE_AGENT);
}

// group flag-sync: monotonic counter; release-add, relaxed spin (thread 0 only)
__device__ __forceinline__ void gsync(unsigned* cnt, unsigned target) {
    __syncthreads();   // all waves drain their stores before arrival
    if (threadIdx.x == 0) {
        __hip_atomic_fetch_add(cnt, 1u, __ATOMIC_RELEASE, __HIP_MEMORY_SCOPE_AGENT);
        while (__hip_atomic_load(cnt, __ATOMIC_RELAXED, __HIP_MEMORY_SCOPE_AGENT) < target)
            __builtin_amdgcn_s_sleep(2);
    }
    __syncthreads();
    asm volatile("" ::: "memory");
}

// ---------------- prep: convert weights f32->bf16, cat gates, bsum, zero states+counters ----
__global__ __launch_bounds__(256)
void prep2(const float* __restrict__ w_ih_l0, const float* __restrict__ w_hh_l0,
           const float* __restrict__ b_ih_l0, const float* __restrict__ b_hh_l0,
           const float* __restrict__ w_ih_l1, const float* __restrict__ w_hh_l1,
           const float* __restrict__ b_ih_l1, const float* __restrict__ b_hh_l1,
           const float* __restrict__ in_proj_w, const float* __restrict__ x_proj_w,
           const float* __restrict__ out_proj_w,
           short* __restrict__ wsu, float* __restrict__ wsf)
{
    const int nt = gridDim.x * blockDim.x;
    const int g0 = blockIdx.x * blockDim.x + threadIdx.x;

    for (int idx = g0; idx < 2*1024*384; idx += nt) {
        int dir = idx / (1024*384), rem = idx % (1024*384);
        int n = rem / 384, k = rem % 384;
        float v = (k < 128) ? w_ih_l0[(size_t)dir*1024*128 + (size_t)n*128 + k]
                            : w_hh_l0[(size_t)dir*1024*256 + (size_t)n*256 + (k-128)];
        wsu[U_WC0 + idx] = f2bs(v);
    }
    for (int idx = g0; idx < 2*1024*768; idx += nt) {
        int dir = idx / (1024*768), rem = idx % (1024*768);
        int n = rem / 768, k = rem % 768;
        float v = (k < 512) ? w_ih_l1[(size_t)dir*1024*512 + (size_t)n*512 + k]
                            : w_hh_l1[(size_t)dir*1024*256 + (size_t)n*256 + (k-512)];
        wsu[U_WC1 + idx] = f2bs(v);
    }
    for (int idx = g0; idx < 1024*256; idx += nt) wsu[U_INP  + idx] = f2bs(in_proj_w[idx]);
    for (int idx = g0; idx < 48*512;   idx += nt) wsu[U_XP   + idx] = f2bs(x_proj_w[idx]);
    for (int idx = g0; idx < 256*512;  idx += nt) wsu[U_OUTP + idx] = f2bs(out_proj_w[idx]);
    for (int idx = g0; idx < 2048; idx += nt) {
        wsf[F_BSUM0 + idx] = b_ih_l0[idx] + b_hh_l0[idx];
        wsf[F_BSUM1 + idx] = b_ih_l1[idx] + b_hh_l1[idx];
    }
    for (int idx = g0; idx < 2*BB*256; idx += nt) {
        wsf[F_H0 + idx] = 0.0f;
        wsf[F_C0 + idx] = 0.0f;
    }
    unsigned* cnt = (unsigned*)(wsf + F_CNT);
    for (int idx = g0; idx < 64; idx += nt) cnt[idx] = 0;
}

// ---------------- cooperative layer kernel: 32 groups x 8 members, 3 syncs/step ----------------
// Member j owns: G1 cols {256q+32j..+32, q=0..3} (gate-aligned -> f/g/o stay local),
// G2 cols 128j..+128, G4 cols 32j..+32 + c/h update. G3+phase4 computed full-redundantly
// from the xm/zs exchange (Wxp LDS-cached) -> no xd/y comm, no 4th sync.
template<int DIN, typename TIn, typename TOut>
__global__ __launch_bounds__(BLK)
void layer_coop(const TIn* __restrict__ in,        // (B,T,DIN)
                TOut* __restrict__ out,             // (B,T,512): dir writes [dir*256,+256)
                const short* __restrict__ Wcat,     // (2,1024,KG) bf16
                const short* __restrict__ Winp,     // (1024,256)
                const short* __restrict__ Wxp,      // (48,512)
                const short* __restrict__ Woutp,    // (256,512)
                const float* __restrict__ bsum_all, // (2,1024)
                const float* __restrict__ conv_w,   // (512,2)
                const float* __restrict__ conv_b,   // (512)
                const float* __restrict__ dtw,      // (512,16)
                const float* __restrict__ dtb,      // (512)
                const float* __restrict__ Dm,       // (512)
                const float* __restrict__ h_init, const float* __restrict__ c_init,
                float* __restrict__ h_fin, float* __restrict__ c_fin,
                unsigned* commAll, unsigned* cntAll, int layer)
{
    constexpr int KG = DIN + 256;
    constexpr int ASTR = DIN + 264;       // sA row stride (shorts); =4 banks mod 32
    constexpr int NU = 16*DIN/BLK;        // u elements per thread
    const int tid = threadIdx.x;
    const int wv = tid >> 6, ln = tid & 63;
    const int lr = ln & 15, lq = ln >> 4;
    // same-XCD group packing (perf heuristic; correctness placement-independent)
    const int bid = blockIdx.x;
    const int xcd = bid & 7, slot = bid >> 3;
    const int g = xcd * 4 + (slot >> 3);           // group 0..31
    const int j = slot & 7;                        // member 0..7
    const int dir = g >> 4;
    const int b0 = (g & 15) * NBR;

    unsigned* cu = commAll + (size_t)g * GSTR;
    unsigned* cnt = cntAll + layer * 32 + g;

    const short* Wg = Wcat + (size_t)dir * 1024 * KG;

    __shared__ __attribute__((aligned(16))) short sA[16*ASTR];   // [u | h]
    __shared__ __attribute__((aligned(16))) short sUm[16*264];   // full um bf16
    __shared__ __attribute__((aligned(16))) short sXm[16*520];   // full xm, y in-place
    __shared__ __attribute__((aligned(16))) short sZs[16*520];   // full silu(z)
    __shared__ __attribute__((aligned(16))) short sWxp[48*520];  // Wxp LDS-cached
    __shared__ __attribute__((aligned(16))) short sLoc[16*132];  // own xz slice bf16
    __shared__ short sUmLoc[16*36], sHloc[16*36];
    __shared__ float sFs[16*36], sGs[16*36], sOs[16*36], sC[16*36];
    __shared__ float sXd[16*52];

    // ---- init ----
    for (int idx = tid; idx < 16*256; idx += BLK) {
        int r = idx >> 8, k = idx & 255;
        sA[r*ASTR + DIN + k] = f2bs(h_init[((size_t)dir*BB + b0 + r)*256 + k]);
    }
    for (int idx = tid; idx < 16*32; idx += BLK) {
        int r = idx >> 5, kk = idx & 31;
        sC[r*36 + kk] = c_init[((size_t)dir*BB + b0 + r)*256 + 32*j + kk];
    }
    for (int idx = tid; idx < 48*512; idx += BLK) {
        int r = idx >> 9, k = idx & 511;
        sWxp[r*520 + k] = Wxp[idx];
    }
    // hoisted per-lane constants
    const int q1 = wv >> 1, sub = wv & 1;
    const int kk1 = 16*sub + lr;                  // G1 local col 0..31
    const int n1 = 256*q1 + 32*j + kk1;           // G1 row/col
    const float bs1 = bsum_all[dir*1024 + n1];
    const int nloc = wv*16 + lr;                  // 0..127
    const int c1 = 128*j + nloc;                  // G2 column
    float cw = 0.f, cb = 0.f;
    if (j < 4) { cw = conv_w[c1*2 + 1]; cb = conv_b[c1]; }
    const int col4 = 32*j + nloc;                 // G4 column (valid wv<2)
    const float bs4 = (wv < 2) ? bsum_all[dir*1024 + col4] : 0.f;
    float w16[16];
    #pragma unroll
    for (int p = 0; p < 16; ++p) w16[p] = dtw[tid*16 + p];
    const float dtbv = dtb[tid], Dmv = Dm[tid];

    // prefetch u for t=0
    TIn utmp[NU];
    {
        const int tn = dir ? (TT-1) : 0;
        #pragma unroll
        for (int qq = 0; qq < NU; ++qq) {
            int idx = tid + qq*BLK;
            int r = idx / DIN, dd = idx % DIN;
            utmp[qq] = in[((size_t)(b0+r)*TT + tn)*DIN + dd];
        }
    }

    unsigned target = 8;

    for (int t = 0; t < TT; ++t) {
        const int t_in = dir ? (TT-1-t) : t;

        // ---- A: u from regs; h from comm (t>0) ----
        #pragma unroll
        for (int qq = 0; qq < NU; ++qq) {
            int idx = tid + qq*BLK;
            int r = idx / DIN, dd = idx % DIN;
            sA[r*ASTR + dd] = conv2bs(utmp[qq]);
        }
        if (t > 0) {
            for (int idx = tid; idx < 16*128; idx += BLK) {
                int r = idx >> 7, kk = idx & 127;
                unsigned u = a_ldu(&cu[C_H + idx]);
                sA[r*ASTR + DIN + 2*kk]     = (short)(u & 0xffff);
                sA[r*ASTR + DIN + 2*kk + 1] = (short)(u >> 16);
            }
        }
        __syncthreads();

        // ---- B: G1 — own 32-col strip of each gate; f/g/o stay in LDS ----
        {
            f4 acc = (f4){0.f,0.f,0.f,0.f};
            const int arow = lr*ASTR + lq*8;
            const short* brow = &Wg[(size_t)n1*KG + lq*8];
            #pragma unroll 4
            for (int k0 = 0; k0 < KG; k0 += 32) {
                bf8 a = *(const bf8*)&sA[arow + k0];
                bf8 b = *(const bf8*)&brow[k0];
                acc = MFMA16(a, b, acc, 0, 0, 0);
            }
            if (q1 == 0) {
                #pragma unroll
                for (int jj = 0; jj < 4; ++jj)
                    sUmLoc[(lq*4+jj)*36 + kk1] = f2bs(acc[jj]);
            } else if (q1 == 1) {
                #pragma unroll
                for (int jj = 0; jj < 4; ++jj)
                    sFs[(lq*4+jj)*36 + kk1] = sigmoidf_(acc[jj] + bs1);
            } else if (q1 == 2) {
                #pragma unroll
                for (int jj = 0; jj < 4; ++jj)
                    sGs[(lq*4+jj)*36 + kk1] = tanhf_(acc[jj] + bs1);
            } else {
                #pragma unroll
                for (int jj = 0; jj < 4; ++jj)
                    sOs[(lq*4+jj)*36 + kk1] = sigmoidf_(acc[jj] + bs1);
            }
        }
        __syncthreads();
        // publish um slice (packed bf16 pairs)
        for (int idx = tid; idx < 256; idx += BLK) {
            int r = idx >> 4, kk = idx & 15;
            unsigned lo = (unsigned short)sUmLoc[r*36 + 2*kk];
            unsigned hi = (unsigned short)sUmLoc[r*36 + 2*kk + 1];
            a_stu(&cu[C_UM + r*128 + 16*j + kk], (hi<<16)|lo);
        }
        gsync(cnt, target); target += 8;   // S1

        // ---- C: stage full um ----
        for (int idx = tid; idx < 16*128; idx += BLK) {
            int r = idx >> 7, kk = idx & 127;
            unsigned u = a_ldu(&cu[C_UM + idx]);
            sUm[r*264 + 2*kk]     = (short)(u & 0xffff);
            sUm[r*264 + 2*kk + 1] = (short)(u >> 16);
        }
        __syncthreads();

        // ---- D: G2 — own 128 cols of xz; conv+silu / silu ----
        {
            f4 acc = (f4){0.f,0.f,0.f,0.f};
            const int arow = lr*264 + lq*8;
            const short* brow = &Winp[(size_t)c1*256 + lq*8];
            #pragma unroll 4
            for (int k0 = 0; k0 < 256; k0 += 32) {
                bf8 a = *(const bf8*)&sUm[arow + k0];
                bf8 b = *(const bf8*)&brow[k0];
                acc = MFMA16(a, b, acc, 0, 0, 0);
            }
            #pragma unroll
            for (int jj = 0; jj < 4; ++jj) {
                float v = acc[jj];
                if (j < 4) v = fmaf(v, cw, cb);
                v = v * sigmoidf_(v);
                sLoc[(lq*4+jj)*132 + nloc] = f2bs(v);
            }
        }
        __syncthreads();
        // publish xm/zs slice (packed)
        for (int idx = tid; idx < 16*64; idx += BLK) {
            int r = idx >> 6, kk = idx & 63;
            unsigned lo = (unsigned short)sLoc[r*132 + 2*kk];
            unsigned hi = (unsigned short)sLoc[r*132 + 2*kk + 1];
            unsigned u = (hi << 16) | lo;
            if (j < 4) a_stu(&cu[C_XM + r*256 + 64*j + kk], u);
            else       a_stu(&cu[C_ZS + r*256 + 64*(j-4) + kk], u);
        }
        gsync(cnt, target); target += 8;   // S2

        // ---- E: stage full xm + zs ----
        for (int idx = tid; idx < 16*256; idx += BLK) {
            int r = idx >> 8, kk = idx & 255;
            unsigned ux = a_ldu(&cu[C_XM + idx]);
            sXm[r*520 + 2*kk]     = (short)(ux & 0xffff);
            sXm[r*520 + 2*kk + 1] = (short)(ux >> 16);
            unsigned uz = a_ldu(&cu[C_ZS + idx]);
            sZs[r*520 + 2*kk]     = (short)(uz & 0xffff);
            sZs[r*520 + 2*kk + 1] = (short)(uz >> 16);
        }
        // prefetch u for t+1 (overlaps G3/phase4)
        if (t + 1 < TT) {
            const int tn = dir ? (TT-2-t) : (t+1);
            #pragma unroll
            for (int qq = 0; qq < NU; ++qq) {
                int idx = tid + qq*BLK;
                int r = idx / DIN, dd = idx % DIN;
                utmp[qq] = in[((size_t)(b0+r)*TT + tn)*DIN + dd];
            }
        }
        __syncthreads();

        // ---- F: G3 full (waves 0..2; B from LDS-cached Wxp) ----
        if (wv < 3) {
            f4 acc = (f4){0.f,0.f,0.f,0.f};
            const int arow = lr*520 + lq*8;
            const short* brow = &sWxp[(wv*16 + lr)*520 + lq*8];
            #pragma unroll 4
            for (int k0 = 0; k0 < 512; k0 += 32) {
                bf8 a = *(const bf8*)&sXm[arow + k0];
                bf8 b = *(const bf8*)&brow[k0];
                acc = MFMA16(a, b, acc, 0, 0, 0);
            }
            #pragma unroll
            for (int jj = 0; jj < 4; ++jj)
                sXd[(lq*4+jj)*52 + wv*16 + lr] = acc[jj];
        }
        __syncthreads();

        // ---- G: phase4 full-redundant — thread owns channel tid across 16 rows ----
        for (int r = 0; r < 16; ++r) {
            float dp = dtbv;
            #pragma unroll
            for (int p = 0; p < 16; ++p) dp = fmaf(sXd[r*52 + p], w16[p], dp);
            float bc = 0.f;
            #pragma unroll
            for (int s = 0; s < 16; ++s) bc = fmaf(sXd[r*52+16+s], sXd[r*52+32+s], bc);
            float xmv = bs2f(sXm[r*520 + tid]);
            float zsv = bs2f(sZs[r*520 + tid]);
            float yv = fmaf(softplusf_(dp), bc, Dmv) * xmv * zsv;
            sXm[r*520 + tid] = f2bs(yv);       // y in-place (own column only)
        }
        __syncthreads();

        // ---- H: G4 — own 32 cols (wv<2); gate combine with LOCAL f/g/o ----
        if (wv < 2) {
            f4 acc = (f4){0.f,0.f,0.f,0.f};
            const int arow = lr*520 + lq*8;
            const short* brow = &Woutp[(size_t)col4*512 + lq*8];
            #pragma unroll 4
            for (int k0 = 0; k0 < 512; k0 += 32) {
                bf8 a = *(const bf8*)&sXm[arow + k0];
                bf8 b = *(const bf8*)&brow[k0];
                acc = MFMA16(a, b, acc, 0, 0, 0);
            }
            #pragma unroll
            for (int jj = 0; jj < 4; ++jj) {
                int r = lq*4 + jj;
                float i_t = sigmoidf_(acc[jj] + bs4);
                float cv = fmaf(sFs[r*36 + nloc], sC[r*36 + nloc], i_t * sGs[r*36 + nloc]);
                sC[r*36 + nloc] = cv;
                float hv = sOs[r*36 + nloc] * tanhf_(cv);
                sHloc[r*36 + nloc] = f2bs(hv);
                storeval(&out[((size_t)(b0+r)*TT + t_in)*512 + (size_t)dir*256 + col4], hv);
            }
        }
        __syncthreads();
        // publish h slice (packed)
        for (int idx = tid; idx < 256; idx += BLK) {
            int r = idx >> 4, kk = idx & 15;
            unsigned lo = (unsigned short)sHloc[r*36 + 2*kk];
            unsigned hi = (unsigned short)sHloc[r*36 + 2*kk + 1];
            a_stu(&cu[C_H + r*128 + 16*j + kk], (hi<<16)|lo);
        }
        gsync(cnt, target); target += 8;   // S3
    }

    // ---- finals: own 32-col slice ----
    for (int idx = tid; idx < 16*32; idx += BLK) {
        int r = idx >> 5, kk = idx & 31;
        size_t dst = ((size_t)dir*BB + b0 + r)*256 + 32*j + kk;
        h_fin[dst] = bs2f(sHloc[r*36 + kk]);
        c_fin[dst] = sC[r*36 + kk];
    }
}

extern "C" void kernel_launch(void* const* d_in, const int* in_sizes, int n_in,
                              void* d_out, int out_size, void* d_ws, size_t ws_size,
                              hipStream_t stream)
{
    const float* x          = (const float*)d_in[0];
    const float* w_ih_l0    = (const float*)d_in[1];
    const float* w_hh_l0    = (const float*)d_in[2];
    const float* b_ih_l0    = (const float*)d_in[3];
    const float* b_hh_l0    = (const float*)d_in[4];
    const float* w_ih_l1    = (const float*)d_in[5];
    const float* w_hh_l1    = (const float*)d_in[6];
    const float* b_ih_l1    = (const float*)d_in[7];
    const float* b_hh_l1    = (const float*)d_in[8];
    const float* in_proj_w  = (const float*)d_in[9];
    const float* conv_w     = (const float*)d_in[10];
    const float* conv_b     = (const float*)d_in[11];
    const float* x_proj_w   = (const float*)d_in[12];
    const float* dt_proj_w  = (const float*)d_in[13];
    const float* dt_proj_b  = (const float*)d_in[14];
    const float* D_m        = (const float*)d_in[15];
    const float* out_proj_w = (const float*)d_in[16];

    short* wsu = (short*)d_ws;
    float* wsf = (float*)((char*)d_ws + FOFF);
    unsigned* cntAll  = (unsigned*)(wsf + F_CNT);
    unsigned* commAll = (unsigned*)(wsf + F_COMM);

    prep2<<<512, 256, 0, stream>>>(
        w_ih_l0, w_hh_l0, b_ih_l0, b_hh_l0,
        w_ih_l1, w_hh_l1, b_ih_l1, b_hh_l1,
        in_proj_w, x_proj_w, out_proj_w, wsu, wsf);

    // layer 0: x fp32 (DIN=128) -> l0out bf16; finals -> H1/C1
    layer_coop<128, float, short><<<256, BLK, 0, stream>>>(
        x, wsu + U_L0,
        wsu + U_WC0, wsu + U_INP, wsu + U_XP, wsu + U_OUTP,
        wsf + F_BSUM0, conv_w, conv_b, dt_proj_w, dt_proj_b, D_m,
        wsf + F_H0, wsf + F_C0, wsf + F_H1, wsf + F_C1,
        commAll, cntAll, 0);

    // layer 1: l0out bf16 (DIN=512) -> d_out fp32; init from H1/C1
    layer_coop<512, short, float><<<256, BLK, 0, stream>>>(
        wsu + U_L0, (float*)d_out,
        wsu + U_WC1, wsu + U_INP, wsu + U_XP, wsu + U_OUTP,
        wsf + F_BSUM1, conv_w, conv_b, dt_proj_w, dt_proj_b, D_m,
        wsf + F_H1, wsf + F_C1, wsf + F_H0, wsf + F_C0,
        commAll, cntAll, 1);
}

// Round 5
// 9407.285 us; speedup vs baseline: 1.9843x; 1.0787x over previous
//
#include <hip/hip_runtime.h>
#include <hip/hip_bf16.h>
#include <math.h>

#define BB 256     // batch
#define TT 128     // timesteps
#define NBR 16     // batch rows per group
#define BLK 512    // threads per block (8 waves)

typedef short bf8 __attribute__((ext_vector_type(8)));   // 8 bf16 (4 VGPRs)
typedef float f4  __attribute__((ext_vector_type(4)));   // MFMA accumulator
#define MFMA16 __builtin_amdgcn_mfma_f32_16x16x32_bf16

// ---- workspace layout (bf16/short element offsets) ----
constexpr size_t U_WC0  = 0;                                   // (2,768,384)  gate-only cat l0
constexpr size_t U_WC1  = U_WC0  + (size_t)2*768*384;          // (2,768,768)  gate-only cat l1
constexpr size_t U_WCB0 = U_WC1  + (size_t)2*768*768;          // (2,1024,384) Wcomb l0
constexpr size_t U_WCB1 = U_WCB0 + (size_t)2*1024*384;         // (2,1024,768) Wcomb l1
constexpr size_t U_XP   = U_WCB1 + (size_t)2*1024*768;         // (48,512)
constexpr size_t U_OUTP = U_XP   + (size_t)48*512;             // (256,512)
constexpr size_t U_L0   = U_OUTP + (size_t)256*512;            // (B,T,512) l0 out bf16
constexpr size_t U_END  = U_L0   + (size_t)BB*TT*512;
constexpr size_t FOFF   = U_END * 2;                           // byte offset of f32 region
// f32 region (float offsets):
constexpr size_t F_BSUM0 = 0;                 // (2,1024)
constexpr size_t F_BSUM1 = F_BSUM0 + 2048;    // (2,1024)
constexpr size_t F_H0    = F_BSUM1 + 2048;    // (2,B,256)
constexpr size_t F_C0    = F_H0 + 2*BB*256;
constexpr size_t F_H1    = F_C0 + 2*BB*256;
constexpr size_t F_C1    = F_H1 + 2*BB*256;
constexpr size_t F_CNT   = F_C1 + 2*BB*256;   // 64 u32 sync counters
constexpr size_t F_COMM  = F_CNT + 64;
// per-group comm block (u32 words; bf16 vertical row-pairs: word = chan*8 + rowpair)
constexpr int C_XM  = 0;        // 512 chan x 8 rowpairs = 4096 u32
constexpr int C_ZS  = 4096;     // 512 chan x 8 = 4096
constexpr int C_H   = 8192;     // 256 chan x 8 = 2048
constexpr int GSTR  = 10240;    // 40KB/group; x32 = 1.25MB

__device__ __forceinline__ short f2bs(float v) {
    __hip_bfloat16 b = __float2bfloat16(v);
    short s; __builtin_memcpy(&s, &b, 2); return s;
}
__device__ __forceinline__ float bs2f(short s) {
    unsigned int u = ((unsigned int)(unsigned short)s) << 16;
    float f; __builtin_memcpy(&f, &u, 4); return f;
}
__device__ __forceinline__ float sigmoidf_(float x) { return 1.0f / (1.0f + __expf(-x)); }
__device__ __forceinline__ float tanhf_(float x) {
    float e = __expf(-2.0f * fabsf(x));
    float t = (1.0f - e) / (1.0f + e);
    return copysignf(t, x);
}
__device__ __forceinline__ float softplusf_(float x) {
    return log1pf(__expf(-fabsf(x))) + fmaxf(x, 0.0f);
}
__device__ __forceinline__ short conv2bs(float v) { return f2bs(v); }
__device__ __forceinline__ short conv2bs(short v) { return v; }
__device__ __forceinline__ void storeval(float* p, float v) { *p = v; }
__device__ __forceinline__ void storeval(short* p, float v) { *p = f2bs(v); }
__device__ __forceinline__ unsigned packbs(float lo, float hi) {
    return (unsigned)(unsigned short)f2bs(lo) | ((unsigned)(unsigned short)f2bs(hi) << 16);
}

// device-scope comm accessors (cross-XCD coherent; proven r3/r4 protocol)
__device__ __forceinline__ void a_stu(unsigned* p, unsigned v) {
    __hip_atomic_store(p, v, __ATOMIC_RELAXED, __HIP_MEMORY_SCOPE_AGENT);
}
__device__ __forceinline__ unsigned a_ldu(unsigned* p) {
    return __hip_atomic_load(p, __ATOMIC_RELAXED, __HIP_MEMORY_SCOPE_AGENT);
}
__device__ __forceinline__ void gsync(unsigned* cnt, unsigned target) {
    __syncthreads();
    if (threadIdx.x == 0) {
        __hip_atomic_fetch_add(cnt, 1u, __ATOMIC_RELEASE, __HIP_MEMORY_SCOPE_AGENT);
        while (__hip_atomic_load(cnt, __ATOMIC_RELAXED, __HIP_MEMORY_SCOPE_AGENT) < target)
            __builtin_amdgcn_s_sleep(2);
    }
    __syncthreads();
    asm volatile("" ::: "memory");
}

// ---------------- prep: gate-only cat, xp/outp bf16, bsum, zero states+counters ----
__global__ __launch_bounds__(256)
void prep2(const float* __restrict__ w_ih_l0, const float* __restrict__ w_hh_l0,
           const float* __restrict__ b_ih_l0, const float* __restrict__ b_hh_l0,
           const float* __restrict__ w_ih_l1, const float* __restrict__ w_hh_l1,
           const float* __restrict__ b_ih_l1, const float* __restrict__ b_hh_l1,
           const float* __restrict__ x_proj_w, const float* __restrict__ out_proj_w,
           short* __restrict__ wsu, float* __restrict__ wsf)
{
    const int nt = gridDim.x * blockDim.x;
    const int g0 = blockIdx.x * blockDim.x + threadIdx.x;

    // gate-only Wcat' l0: (2,768,384), source rows 256..1023
    for (int idx = g0; idx < 2*768*384; idx += nt) {
        int dir = idx / (768*384), rem = idx % (768*384);
        int n = rem / 384, k = rem % 384, row = 256 + n;
        float v = (k < 128) ? w_ih_l0[(size_t)dir*1024*128 + (size_t)row*128 + k]
                            : w_hh_l0[(size_t)dir*1024*256 + (size_t)row*256 + (k-128)];
        wsu[U_WC0 + idx] = f2bs(v);
    }
    // gate-only Wcat' l1: (2,768,768)
    for (int idx = g0; idx < 2*768*768; idx += nt) {
        int dir = idx / (768*768), rem = idx % (768*768);
        int n = rem / 768, k = rem % 768, row = 256 + n;
        float v = (k < 512) ? w_ih_l1[(size_t)dir*1024*512 + (size_t)row*512 + k]
                            : w_hh_l1[(size_t)dir*1024*256 + (size_t)row*256 + (k-512)];
        wsu[U_WC1 + idx] = f2bs(v);
    }
    for (int idx = g0; idx < 48*512;  idx += nt) wsu[U_XP   + idx] = f2bs(x_proj_w[idx]);
    for (int idx = g0; idx < 256*512; idx += nt) wsu[U_OUTP + idx] = f2bs(out_proj_w[idx]);
    for (int idx = g0; idx < 2048; idx += nt) {
        wsf[F_BSUM0 + idx] = b_ih_l0[idx] + b_hh_l0[idx];
        wsf[F_BSUM1 + idx] = b_ih_l1[idx] + b_hh_l1[idx];
    }
    for (int idx = g0; idx < 2*BB*256; idx += nt) {
        wsf[F_H0 + idx] = 0.0f;
        wsf[F_C0 + idx] = 0.0f;
    }
    unsigned* cnt = (unsigned*)(wsf + F_CNT);
    for (int idx = g0; idx < 64; idx += nt) cnt[idx] = 0;
}

// ---------------- Wcomb = in_proj_w(1024x256) @ Wcat_um(2,256,KG), f32, ->bf16 ----
template<int DIN>
__global__ __launch_bounds__(256)
void wcomb_gemm(const float* __restrict__ inp,   // (1024,256)
                const float* __restrict__ wih,   // (2,1024,DIN)
                const float* __restrict__ whh,   // (2,1024,256)
                short* __restrict__ outw)        // (2,1024,KG)
{
    constexpr int KG = DIN + 256;
    __shared__ float As[16][17], Bs[16][17];
    const int tx = threadIdx.x & 15, ty = threadIdx.x >> 4;
    const int n = blockIdx.x*16 + ty;
    const int k = blockIdx.y*16 + tx;
    const int dir = blockIdx.z;
    float acc = 0.f;
    for (int m0 = 0; m0 < 256; m0 += 16) {
        As[ty][tx] = inp[(size_t)n*256 + m0 + tx];
        int m = m0 + ty;   // um source row (0..255)
        Bs[ty][tx] = (k < DIN) ? wih[((size_t)dir*1024 + m)*DIN + k]
                               : whh[((size_t)dir*1024 + m)*256 + (k - DIN)];
        __syncthreads();
        #pragma unroll
        for (int mm = 0; mm < 16; ++mm) acc = fmaf(As[ty][mm], Bs[mm][tx], acc);
        __syncthreads();
    }
    outw[((size_t)dir*1024 + n)*KG + k] = f2bs(acc);
}

// ---------------- cooperative layer kernel: 32 groups x 8 members, 2 syncs/step ----------------
// Member j owns: G1 f/g/o strips {256q+32j..+32}, fused-G2 cols 128j..+128 (xz via Wcomb),
// G4 cols 32j..+32 + c/h. G3+phase4 full-redundant. Woutp slice LDS-cached.
template<int DIN, typename TIn, typename TOut>
__global__ __launch_bounds__(BLK)
void layer_coop(const TIn* __restrict__ in,        // (B,T,DIN)
                TOut* __restrict__ out,             // (B,T,512): dir writes [dir*256,+256)
                const short* __restrict__ Wg_,      // (2,768,KG) gate-only bf16
                const short* __restrict__ Wcb_,     // (2,1024,KG) Wcomb bf16
                const short* __restrict__ Wxp,      // (48,512)
                const short* __restrict__ Woutp,    // (256,512)
                const float* __restrict__ bsum_all, // (2,1024)
                const float* __restrict__ conv_w,   // (512,2)
                const float* __restrict__ conv_b,   // (512)
                const float* __restrict__ dtw,      // (512,16)
                const float* __restrict__ dtb,      // (512)
                const float* __restrict__ Dm,       // (512)
                const float* __restrict__ h_init, const float* __restrict__ c_init,
                float* __restrict__ h_fin, float* __restrict__ c_fin,
                unsigned* commAll, unsigned* cntAll, int layer)
{
    constexpr int KG = DIN + 256;
    constexpr int ASTR = DIN + 264;       // sA row stride (shorts)
    constexpr int NU = 16*DIN/BLK;        // u elems per thread
    const int tid = threadIdx.x;
    const int wv = tid >> 6, ln = tid & 63;
    const int lr = ln & 15, lq = ln >> 4;
    const int bid = blockIdx.x;
    const int xcd = bid & 7, slot = bid >> 3;
    const int g = xcd * 4 + (slot >> 3);           // group 0..31 (same-XCD packing heuristic)
    const int j = slot & 7;                        // member 0..7
    const int dir = g >> 4;
    const int b0 = (g & 15) * NBR;

    unsigned* cu = commAll + (size_t)g * GSTR;
    unsigned* cnt = cntAll + layer * 32 + g;

    const short* Wg  = Wg_  + (size_t)dir * 768  * KG;
    const short* Wcb = Wcb_ + (size_t)dir * 1024 * KG;

    __shared__ __attribute__((aligned(16))) short sA[16*ASTR];   // [u | h]
    __shared__ __attribute__((aligned(16))) short sXm[16*520];   // full xm, y in-place
    __shared__ __attribute__((aligned(16))) short sZs[16*520];   // full silu(z)
    __shared__ __attribute__((aligned(16))) short sWxp[48*520];  // Wxp cached
    __shared__ __attribute__((aligned(16))) short sWo[32*520];   // Woutp own 32 rows cached
    __shared__ float sFs[16*36], sGs[16*36], sOs[16*36], sC[16*36];
    __shared__ float sXd[16*52];

    // ---- init ----
    for (int idx = tid; idx < 16*256; idx += BLK) {
        int r = idx >> 8, k = idx & 255;
        sA[r*ASTR + DIN + k] = f2bs(h_init[((size_t)dir*BB + b0 + r)*256 + k]);
    }
    for (int idx = tid; idx < 16*32; idx += BLK) {
        int r = idx >> 5, kk = idx & 31;
        sC[r*36 + kk] = c_init[((size_t)dir*BB + b0 + r)*256 + 32*j + kk];
    }
    for (int idx = tid; idx < 48*512; idx += BLK) {
        int r = idx >> 9, k = idx & 511;
        sWxp[r*520 + k] = Wxp[idx];
    }
    for (int idx = tid; idx < 32*512; idx += BLK) {
        int r = idx >> 9, k = idx & 511;
        sWo[r*520 + k] = Woutp[(size_t)(32*j + r)*512 + k];
    }
    // per-lane constants
    const int q1 = wv >> 1, sub = wv & 1;
    const int kk1 = 16*sub + lr;                   // local col in own 32-strip (G1, wv<6)
    const int n1 = 256*q1 + 32*j + kk1;            // gate-only Wcat' row
    const float bs1 = (wv < 6) ? bsum_all[dir*1024 + 256 + n1] : 0.f;
    const int ncl = 16*wv + lr;                    // fused-G2 local col 0..127
    const int c1 = 128*j + ncl;                    // xz channel (0..511 per half)
    float cw = 0.f, cb = 0.f;
    if (j < 4) { cw = conv_w[c1*2 + 1]; cb = conv_b[c1]; }
    const int nloc = wv*16 + lr;                   // G4 local col (valid wv<2)
    const int col4 = 32*j + nloc;
    const float bs4 = (wv < 2) ? bsum_all[dir*1024 + col4] : 0.f;
    float w16[16];
    #pragma unroll
    for (int p = 0; p < 16; ++p) w16[p] = dtw[tid*16 + p];
    const float dtbv = dtb[tid], Dmv = Dm[tid];

    // prefetch u for t=0
    TIn utmp[NU];
    {
        const int tn = dir ? (TT-1) : 0;
        #pragma unroll
        for (int qq = 0; qq < NU; ++qq) {
            int idx = tid + qq*BLK;
            int r = idx / DIN, dd = idx % DIN;
            utmp[qq] = in[((size_t)(b0+r)*TT + tn)*DIN + dd];
        }
    }

    unsigned target = 8;

    for (int t = 0; t < TT; ++t) {
        const int t_in = dir ? (TT-1-t) : t;

        // ---- A: u from regs; h from comm (t>0) ----
        #pragma unroll
        for (int qq = 0; qq < NU; ++qq) {
            int idx = tid + qq*BLK;
            int r = idx / DIN, dd = idx % DIN;
            sA[r*ASTR + dd] = conv2bs(utmp[qq]);
        }
        if (t > 0) {
            for (int idx = tid; idx < 2048; idx += BLK) {
                int col = idx >> 3, rp = idx & 7;
                unsigned u = a_ldu(&cu[C_H + idx]);
                sA[(2*rp)*ASTR   + DIN + col] = (short)(u & 0xffff);
                sA[(2*rp+1)*ASTR + DIN + col] = (short)(u >> 16);
            }
        }
        __syncthreads();

        // ---- B: fused G1(f/g/o strips, wv<6) + G2'(xz via Wcomb, all waves), K=KG ----
        {
            f4 accG = (f4){0.f,0.f,0.f,0.f};
            f4 accC = (f4){0.f,0.f,0.f,0.f};
            const int arow = lr*ASTR + lq*8;
            const short* browG = &Wg[(size_t)(wv < 6 ? n1 : 0)*KG + lq*8];
            const short* browC = &Wcb[(size_t)c1*KG + lq*8];
            #pragma unroll 4
            for (int k0 = 0; k0 < KG; k0 += 32) {
                bf8 a = *(const bf8*)&sA[arow + k0];
                if (wv < 6) {
                    bf8 bg = *(const bf8*)&browG[k0];
                    accG = MFMA16(a, bg, accG, 0, 0, 0);
                }
                bf8 bc = *(const bf8*)&browC[k0];
                accC = MFMA16(a, bc, accC, 0, 0, 0);
            }
            // G2' epilogue: conv+silu (xm) / silu (z); publish vertical row-pairs
            float vv[4];
            #pragma unroll
            for (int jj = 0; jj < 4; ++jj) {
                float v = accC[jj];
                if (j < 4) v = fmaf(v, cw, cb);
                vv[jj] = v * sigmoidf_(v);
            }
            unsigned* dst = (j < 4) ? &cu[C_XM + c1*8] : &cu[C_ZS + (c1-512+512*(j<4))*8];
            // note: for j>=4, channel = c1-512
            if (j < 4) {
                a_stu(&cu[C_XM + c1*8 + lq*2],     packbs(vv[0], vv[1]));
                a_stu(&cu[C_XM + c1*8 + lq*2 + 1], packbs(vv[2], vv[3]));
            } else {
                int cz = c1 - 512;
                a_stu(&cu[C_ZS + cz*8 + lq*2],     packbs(vv[0], vv[1]));
                a_stu(&cu[C_ZS + cz*8 + lq*2 + 1], packbs(vv[2], vv[3]));
            }
            (void)dst;
            // G1 epilogue: activated gates into local LDS strips
            if (wv < 6) {
                #pragma unroll
                for (int jj = 0; jj < 4; ++jj) {
                    float v = accG[jj] + bs1;
                    int rr = lq*4 + jj;
                    if (q1 == 0)      sFs[rr*36 + kk1] = sigmoidf_(v);
                    else if (q1 == 1) sGs[rr*36 + kk1] = tanhf_(v);
                    else              sOs[rr*36 + kk1] = sigmoidf_(v);
                }
            }
        }
        gsync(cnt, target); target += 8;   // S_a: xm/zs exchanged

        // ---- C: stage full xm + zs ----
        for (int idx = tid; idx < 4096; idx += BLK) {
            int col = idx >> 3, rp = idx & 7;
            unsigned ux = a_ldu(&cu[C_XM + idx]);
            sXm[(2*rp)*520   + col] = (short)(ux & 0xffff);
            sXm[(2*rp+1)*520 + col] = (short)(ux >> 16);
            unsigned uz = a_ldu(&cu[C_ZS + idx]);
            sZs[(2*rp)*520   + col] = (short)(uz & 0xffff);
            sZs[(2*rp+1)*520 + col] = (short)(uz >> 16);
        }
        // prefetch u for t+1 (overlaps G3/phase4)
        if (t + 1 < TT) {
            const int tn = dir ? (TT-2-t) : (t+1);
            #pragma unroll
            for (int qq = 0; qq < NU; ++qq) {
                int idx = tid + qq*BLK;
                int r = idx / DIN, dd = idx % DIN;
                utmp[qq] = in[((size_t)(b0+r)*TT + tn)*DIN + dd];
            }
        }
        __syncthreads();

        // ---- D: G3 full (waves 0..2; LDS-cached Wxp) ----
        if (wv < 3) {
            f4 acc = (f4){0.f,0.f,0.f,0.f};
            const int arow = lr*520 + lq*8;
            const short* brow = &sWxp[(wv*16 + lr)*520 + lq*8];
            #pragma unroll 4
            for (int k0 = 0; k0 < 512; k0 += 32) {
                bf8 a = *(const bf8*)&sXm[arow + k0];
                bf8 b = *(const bf8*)&brow[k0];
                acc = MFMA16(a, b, acc, 0, 0, 0);
            }
            #pragma unroll
            for (int jj = 0; jj < 4; ++jj)
                sXd[(lq*4+jj)*52 + wv*16 + lr] = acc[jj];
        }
        __syncthreads();

        // ---- E: phase4 full-redundant — thread owns channel tid across 16 rows ----
        for (int r = 0; r < 16; ++r) {
            float dp = dtbv;
            #pragma unroll
            for (int p = 0; p < 16; ++p) dp = fmaf(sXd[r*52 + p], w16[p], dp);
            float bc = 0.f;
            #pragma unroll
            for (int s = 0; s < 16; ++s) bc = fmaf(sXd[r*52+16+s], sXd[r*52+32+s], bc);
            float xmv = bs2f(sXm[r*520 + tid]);
            float zsv = bs2f(sZs[r*520 + tid]);
            float yv = fmaf(softplusf_(dp), bc, Dmv) * xmv * zsv;
            sXm[r*520 + tid] = f2bs(yv);       // y in-place
        }
        __syncthreads();

        // ---- F: G4 — own 32 cols (wv<2, LDS-cached Woutp); c/h update; publish h ----
        if (wv < 2) {
            f4 acc = (f4){0.f,0.f,0.f,0.f};
            const int arow = lr*520 + lq*8;
            const short* brow = &sWo[nloc*520 + lq*8];
            #pragma unroll 4
            for (int k0 = 0; k0 < 512; k0 += 32) {
                bf8 a = *(const bf8*)&sXm[arow + k0];
                bf8 b = *(const bf8*)&brow[k0];
                acc = MFMA16(a, b, acc, 0, 0, 0);
            }
            float hvv[4];
            #pragma unroll
            for (int jj = 0; jj < 4; ++jj) {
                int r = lq*4 + jj;
                float i_t = sigmoidf_(acc[jj] + bs4);
                float cv = fmaf(sFs[r*36 + nloc], sC[r*36 + nloc], i_t * sGs[r*36 + nloc]);
                sC[r*36 + nloc] = cv;
                float hv = sOs[r*36 + nloc] * tanhf_(cv);
                hvv[jj] = hv;
                storeval(&out[((size_t)(b0+r)*TT + t_in)*512 + (size_t)dir*256 + col4], hv);
            }
            a_stu(&cu[C_H + col4*8 + lq*2],     packbs(hvv[0], hvv[1]));
            a_stu(&cu[C_H + col4*8 + lq*2 + 1], packbs(hvv[2], hvv[3]));
        }
        gsync(cnt, target); target += 8;   // S_b: h exchanged
    }

    // ---- finals: own 32-col slice (h from comm, c from LDS) ----
    for (int idx = tid; idx < 16*32; idx += BLK) {
        int r = idx >> 5, kk = idx & 31;
        int col = 32*j + kk;
        unsigned u = a_ldu(&cu[C_H + col*8 + (r >> 1)]);
        short s = (r & 1) ? (short)(u >> 16) : (short)(u & 0xffff);
        size_t dst = ((size_t)dir*BB + b0 + r)*256 + col;
        h_fin[dst] = bs2f(s);
        c_fin[dst] = sC[r*36 + kk];
    }
}

extern "C" void kernel_launch(void* const* d_in, const int* in_sizes, int n_in,
                              void* d_out, int out_size, void* d_ws, size_t ws_size,
                              hipStream_t stream)
{
    const float* x          = (const float*)d_in[0];
    const float* w_ih_l0    = (const float*)d_in[1];
    const float* w_hh_l0    = (const float*)d_in[2];
    const float* b_ih_l0    = (const float*)d_in[3];
    const float* b_hh_l0    = (const float*)d_in[4];
    const float* w_ih_l1    = (const float*)d_in[5];
    const float* w_hh_l1    = (const float*)d_in[6];
    const float* b_ih_l1    = (const float*)d_in[7];
    const float* b_hh_l1    = (const float*)d_in[8];
    const float* in_proj_w  = (const float*)d_in[9];
    const float* conv_w     = (const float*)d_in[10];
    const float* conv_b     = (const float*)d_in[11];
    const float* x_proj_w   = (const float*)d_in[12];
    const float* dt_proj_w  = (const float*)d_in[13];
    const float* dt_proj_b  = (const float*)d_in[14];
    const float* D_m        = (const float*)d_in[15];
    const float* out_proj_w = (const float*)d_in[16];

    short* wsu = (short*)d_ws;
    float* wsf = (float*)((char*)d_ws + FOFF);
    unsigned* cntAll  = (unsigned*)(wsf + F_CNT);
    unsigned* commAll = (unsigned*)(wsf + F_COMM);

    prep2<<<512, 256, 0, stream>>>(
        w_ih_l0, w_hh_l0, b_ih_l0, b_hh_l0,
        w_ih_l1, w_hh_l1, b_ih_l1, b_hh_l1,
        x_proj_w, out_proj_w, wsu, wsf);

    // Wcomb = in_proj_w @ Wcat_um (f32 accumulate, bf16 store)
    {
        dim3 g0(1024/16, 384/16, 2);
        wcomb_gemm<128><<<g0, 256, 0, stream>>>(in_proj_w, w_ih_l0, w_hh_l0, wsu + U_WCB0);
        dim3 g1(1024/16, 768/16, 2);
        wcomb_gemm<512><<<g1, 256, 0, stream>>>(in_proj_w, w_ih_l1, w_hh_l1, wsu + U_WCB1);
    }

    // layer 0: x fp32 (DIN=128) -> l0out bf16; finals -> H1/C1
    layer_coop<128, float, short><<<256, BLK, 0, stream>>>(
        x, wsu + U_L0,
        wsu + U_WC0, wsu + U_WCB0, wsu + U_XP, wsu + U_OUTP,
        wsf + F_BSUM0, conv_w, conv_b, dt_proj_w, dt_proj_b, D_m,
        wsf + F_H0, wsf + F_C0, wsf + F_H1, wsf + F_C1,
        commAll, cntAll, 0);

    // layer 1: l0out bf16 (DIN=512) -> d_out fp32; init from H1/C1
    layer_coop<512, short, float><<<256, BLK, 0, stream>>>(
        wsu + U_L0, (float*)d_out,
        wsu + U_WC1, wsu + U_WCB1, wsu + U_XP, wsu + U_OUTP,
        wsf + F_BSUM1, conv_w, conv_b, dt_proj_w, dt_proj_b, D_m,
        wsf + F_H1, wsf + F_C1, wsf + F_H0, wsf + F_C0,
        commAll, cntAll, 1);
}

// Round 6
// 5970.268 us; speedup vs baseline: 3.1266x; 1.5757x over previous
//
#include <hip/hip_runtime.h>
#include <hip/hip_bf16.h>
#include <math.h>

#define BB 256     // batch
#define TT 128     // timesteps
#define NBR 16     // batch rows per group
#define BLK 512    // threads per block (8 waves)

typedef short bf8 __attribute__((ext_vector_type(8)));   // 8 bf16 (4 VGPRs)
typedef float f4  __attribute__((ext_vector_type(4)));   // MFMA accumulator
typedef unsigned long long u64;
#define MFMA16 __builtin_amdgcn_mfma_f32_16x16x32_bf16

// ---- workspace layout (bf16/short element offsets) ----
constexpr size_t U_WC0  = 0;                                   // (2,768,384)  gate-only cat l0
constexpr size_t U_WC1  = U_WC0  + (size_t)2*768*384;          // (2,768,768)  gate-only cat l1
constexpr size_t U_WCB0 = U_WC1  + (size_t)2*768*768;          // (2,1024,384) Wcomb l0
constexpr size_t U_WCB1 = U_WCB0 + (size_t)2*1024*384;         // (2,1024,768) Wcomb l1
constexpr size_t U_XP   = U_WCB1 + (size_t)2*1024*768;         // (48,512)
constexpr size_t U_OUTP = U_XP   + (size_t)48*512;             // (256,512)
constexpr size_t U_L0   = U_OUTP + (size_t)256*512;            // (B,T,512) l0 out bf16
constexpr size_t U_END  = U_L0   + (size_t)BB*TT*512;
constexpr size_t FOFF   = U_END * 2;                           // byte offset of f32 region
// f32 region (float offsets):
constexpr size_t F_BSUM0 = 0;                 // (2,1024)
constexpr size_t F_BSUM1 = F_BSUM0 + 2048;    // (2,1024)
constexpr size_t F_H0    = F_BSUM1 + 2048;    // (2,B,256)
constexpr size_t F_C0    = F_H0 + 2*BB*256;
constexpr size_t F_H1    = F_C0 + 2*BB*256;
constexpr size_t F_C1    = F_H1 + 2*BB*256;
constexpr size_t F_CNT   = F_C1 + 2*BB*256;   // 64 counters x 64-word pad (256B each)
constexpr size_t F_COMM  = F_CNT + 4096;
// per-group comm block, u64 words; one u64 = 4 bf16 rows (lane's 4 acc rows) of one channel
constexpr int X_XM  = 0;        // 512 chan x 4 quads = 2048 u64
constexpr int X_ZS  = 2048;     // 2048 u64
constexpr int X_H   = 4096;     // 256 chan x 4 = 1024 u64
constexpr int GSTR  = 5120;     // 40KB/group; x32 = 1.25MB

__device__ __forceinline__ short f2bs(float v) {
    __hip_bfloat16 b = __float2bfloat16(v);
    short s; __builtin_memcpy(&s, &b, 2); return s;
}
__device__ __forceinline__ float bs2f(short s) {
    unsigned int u = ((unsigned int)(unsigned short)s) << 16;
    float f; __builtin_memcpy(&f, &u, 4); return f;
}
__device__ __forceinline__ float sigmoidf_(float x) { return 1.0f / (1.0f + __expf(-x)); }
__device__ __forceinline__ float tanhf_(float x) {
    float e = __expf(-2.0f * fabsf(x));
    float t = (1.0f - e) / (1.0f + e);
    return copysignf(t, x);
}
__device__ __forceinline__ float softplusf_(float x) {
    return log1pf(__expf(-fabsf(x))) + fmaxf(x, 0.0f);
}
__device__ __forceinline__ short conv2bs(float v) { return f2bs(v); }
__device__ __forceinline__ short conv2bs(short v) { return v; }
__device__ __forceinline__ void storeval(float* p, float v) { *p = v; }
__device__ __forceinline__ void storeval(short* p, float v) { *p = f2bs(v); }
__device__ __forceinline__ u64 pack4(float a, float b, float c, float d) {
    unsigned lo = (unsigned)(unsigned short)f2bs(a) | ((unsigned)(unsigned short)f2bs(b) << 16);
    unsigned hi = (unsigned)(unsigned short)f2bs(c) | ((unsigned)(unsigned short)f2bs(d) << 16);
    return (u64)lo | ((u64)hi << 32);
}
__device__ __forceinline__ short sel4(u64 v, int s) { return (short)(v >> (16*s)); }

// device-scope (cross-XCD coherent) comm accessors, 8-byte
__device__ __forceinline__ void a_stU(u64* p, u64 v) {
    __hip_atomic_store(p, v, __ATOMIC_RELAXED, __HIP_MEMORY_SCOPE_AGENT);
}
__device__ __forceinline__ u64 a_ldU(u64* p) {
    return __hip_atomic_load(p, __ATOMIC_RELAXED, __HIP_MEMORY_SCOPE_AGENT);
}
// group flag-sync. RELAXED add is sufficient: all data stores are agent-scope and each
// wave's __syncthreads drains vmcnt(0) before the barrier, so data is at the coherence
// point before thread0 issues the add (in-order issue). Avoids the per-release L2
// writeback the compiler must otherwise emit at agent scope.
__device__ __forceinline__ void gsync(unsigned* cnt, unsigned target) {
    __syncthreads();
    if (threadIdx.x == 0) {
        __hip_atomic_fetch_add(cnt, 1u, __ATOMIC_RELAXED, __HIP_MEMORY_SCOPE_AGENT);
        while (__hip_atomic_load(cnt, __ATOMIC_RELAXED, __HIP_MEMORY_SCOPE_AGENT) < target)
            __builtin_amdgcn_s_sleep(1);
    }
    __syncthreads();
    asm volatile("" ::: "memory");
}

// ---------------- prep: gate-only cat, xp/outp bf16, bsum, zero states+counters ----
__global__ __launch_bounds__(256)
void prep2(const float* __restrict__ w_ih_l0, const float* __restrict__ w_hh_l0,
           const float* __restrict__ b_ih_l0, const float* __restrict__ b_hh_l0,
           const float* __restrict__ w_ih_l1, const float* __restrict__ w_hh_l1,
           const float* __restrict__ b_ih_l1, const float* __restrict__ b_hh_l1,
           const float* __restrict__ x_proj_w, const float* __restrict__ out_proj_w,
           short* __restrict__ wsu, float* __restrict__ wsf)
{
    const int nt = gridDim.x * blockDim.x;
    const int g0 = blockIdx.x * blockDim.x + threadIdx.x;

    // gate-only Wcat' l0: (2,768,384), source rows 256..1023
    for (int idx = g0; idx < 2*768*384; idx += nt) {
        int dir = idx / (768*384), rem = idx % (768*384);
        int n = rem / 384, k = rem % 384, row = 256 + n;
        float v = (k < 128) ? w_ih_l0[(size_t)dir*1024*128 + (size_t)row*128 + k]
                            : w_hh_l0[(size_t)dir*1024*256 + (size_t)row*256 + (k-128)];
        wsu[U_WC0 + idx] = f2bs(v);
    }
    // gate-only Wcat' l1: (2,768,768)
    for (int idx = g0; idx < 2*768*768; idx += nt) {
        int dir = idx / (768*768), rem = idx % (768*768);
        int n = rem / 768, k = rem % 768, row = 256 + n;
        float v = (k < 512) ? w_ih_l1[(size_t)dir*1024*512 + (size_t)row*512 + k]
                            : w_hh_l1[(size_t)dir*1024*256 + (size_t)row*256 + (k-512)];
        wsu[U_WC1 + idx] = f2bs(v);
    }
    for (int idx = g0; idx < 48*512;  idx += nt) wsu[U_XP   + idx] = f2bs(x_proj_w[idx]);
    for (int idx = g0; idx < 256*512; idx += nt) wsu[U_OUTP + idx] = f2bs(out_proj_w[idx]);
    for (int idx = g0; idx < 2048; idx += nt) {
        wsf[F_BSUM0 + idx] = b_ih_l0[idx] + b_hh_l0[idx];
        wsf[F_BSUM1 + idx] = b_ih_l1[idx] + b_hh_l1[idx];
    }
    for (int idx = g0; idx < 2*BB*256; idx += nt) {
        wsf[F_H0 + idx] = 0.0f;
        wsf[F_C0 + idx] = 0.0f;
    }
    unsigned* cnt = (unsigned*)(wsf + F_CNT);
    for (int idx = g0; idx < 4096; idx += nt) cnt[idx] = 0;
}

// ---------------- Wcomb = in_proj_w(1024x256) @ Wcat_um(2,256,KG), f32, ->bf16 ----
template<int DIN>
__global__ __launch_bounds__(256)
void wcomb_gemm(const float* __restrict__ inp,   // (1024,256)
                const float* __restrict__ wih,   // (2,1024,DIN)
                const float* __restrict__ whh,   // (2,1024,256)
                short* __restrict__ outw)        // (2,1024,KG)
{
    constexpr int KG = DIN + 256;
    __shared__ float As[16][17], Bs[16][17];
    const int tx = threadIdx.x & 15, ty = threadIdx.x >> 4;
    const int n = blockIdx.x*16 + ty;
    const int k = blockIdx.y*16 + tx;
    const int dir = blockIdx.z;
    float acc = 0.f;
    for (int m0 = 0; m0 < 256; m0 += 16) {
        As[ty][tx] = inp[(size_t)n*256 + m0 + tx];
        int m = m0 + ty;   // um source row (0..255)
        Bs[ty][tx] = (k < DIN) ? wih[((size_t)dir*1024 + m)*DIN + k]
                               : whh[((size_t)dir*1024 + m)*256 + (k - DIN)];
        __syncthreads();
        #pragma unroll
        for (int mm = 0; mm < 16; ++mm) acc = fmaf(As[ty][mm], Bs[mm][tx], acc);
        __syncthreads();
    }
    outw[((size_t)dir*1024 + n)*KG + k] = f2bs(acc);
}

// ---------------- cooperative layer kernel: 32 groups x 8 members, 2 syncs/step ----------------
template<int DIN, typename TIn, typename TOut>
__global__ __launch_bounds__(BLK)
void layer_coop(const TIn* __restrict__ in,        // (B,T,DIN)
                TOut* __restrict__ out,             // (B,T,512): dir writes [dir*256,+256)
                const short* __restrict__ Wg_,      // (2,768,KG) gate-only bf16
                const short* __restrict__ Wcb_,     // (2,1024,KG) Wcomb bf16
                const short* __restrict__ Wxp,      // (48,512)
                const short* __restrict__ Woutp,    // (256,512)
                const float* __restrict__ bsum_all, // (2,1024)
                const float* __restrict__ conv_w,   // (512,2)
                const float* __restrict__ conv_b,   // (512)
                const float* __restrict__ dtw,      // (512,16)
                const float* __restrict__ dtb,      // (512)
                const float* __restrict__ Dm,       // (512)
                const float* __restrict__ h_init, const float* __restrict__ c_init,
                float* __restrict__ h_fin, float* __restrict__ c_fin,
                u64* commAll, unsigned* cntAll, int layer)
{
    constexpr int KG = DIN + 256;
    constexpr int ASTR = DIN + 264;       // sA row stride (shorts)
    constexpr int NU = 16*DIN/BLK;        // u elems per thread
    const int tid = threadIdx.x;
    const int wv = tid >> 6, ln = tid & 63;
    const int lr = ln & 15, lq = ln >> 4;
    const int bid = blockIdx.x;
    const int xcd = bid & 7, slot = bid >> 3;
    const int g = xcd * 4 + (slot >> 3);           // group 0..31 (same-XCD packing heuristic)
    const int j = slot & 7;                        // member 0..7
    const int dir = g >> 4;
    const int b0 = (g & 15) * NBR;

    u64* cu = commAll + (size_t)g * GSTR;
    unsigned* cnt = cntAll + (layer * 32 + g) * 64;   // 256B-padded counter: no false sharing

    const short* Wg  = Wg_  + (size_t)dir * 768  * KG;
    const short* Wcb = Wcb_ + (size_t)dir * 1024 * KG;

    __shared__ __attribute__((aligned(16))) short sA[16*ASTR];   // [u | h]
    __shared__ __attribute__((aligned(16))) short sXm[16*520];   // full xm, y in-place
    __shared__ __attribute__((aligned(16))) short sZs[16*520];   // full silu(z)
    __shared__ __attribute__((aligned(16))) short sWxp[48*520];  // Wxp cached
    __shared__ __attribute__((aligned(16))) short sWo[32*520];   // Woutp own 32 rows cached
    __shared__ float sFs[16*36], sGs[16*36], sOs[16*36], sC[16*36];
    __shared__ float sXd[16*52];

    // ---- init ----
    for (int idx = tid; idx < 16*256; idx += BLK) {
        int r = idx >> 8, k = idx & 255;
        sA[r*ASTR + DIN + k] = f2bs(h_init[((size_t)dir*BB + b0 + r)*256 + k]);
    }
    for (int idx = tid; idx < 16*32; idx += BLK) {
        int r = idx >> 5, kk = idx & 31;
        sC[r*36 + kk] = c_init[((size_t)dir*BB + b0 + r)*256 + 32*j + kk];
    }
    for (int idx = tid; idx < 48*512; idx += BLK) {
        int r = idx >> 9, k = idx & 511;
        sWxp[r*520 + k] = Wxp[idx];
    }
    for (int idx = tid; idx < 32*512; idx += BLK) {
        int r = idx >> 9, k = idx & 511;
        sWo[r*520 + k] = Woutp[(size_t)(32*j + r)*512 + k];
    }
    // per-lane constants
    const int q1 = wv >> 1, sub = wv & 1;
    const int kk1 = 16*sub + lr;                   // local col in own 32-strip (G1, wv<6)
    const int n1 = 256*q1 + 32*j + kk1;            // gate-only Wcat' row
    const float bs1 = (wv < 6) ? bsum_all[dir*1024 + 256 + n1] : 0.f;
    const int ncl = 16*wv + lr;                    // fused-G2 local col 0..127
    const int c1 = 128*j + ncl;                    // xz channel
    float cw = 0.f, cb = 0.f;
    if (j < 4) { cw = conv_w[c1*2 + 1]; cb = conv_b[c1]; }
    const int nloc = wv*16 + lr;                   // G4 local col (valid wv<2)
    const int col4 = 32*j + nloc;
    const float bs4 = (wv < 2) ? bsum_all[dir*1024 + col4] : 0.f;
    float w16[16];
    #pragma unroll
    for (int p = 0; p < 16; ++p) w16[p] = dtw[tid*16 + p];
    const float dtbv = dtb[tid], Dmv = Dm[tid];

    // prefetch u(0) and stage it into sA now (off the in-loop critical path)
    TIn utmp[NU];
    {
        const int tn = dir ? (TT-1) : 0;
        #pragma unroll
        for (int qq = 0; qq < NU; ++qq) {
            int idx = tid + qq*BLK;
            int r = idx / DIN, dd = idx % DIN;
            utmp[qq] = in[((size_t)(b0+r)*TT + tn)*DIN + dd];
        }
        #pragma unroll
        for (int qq = 0; qq < NU; ++qq) {
            int idx = tid + qq*BLK;
            int r = idx / DIN, dd = idx % DIN;
            sA[r*ASTR + dd] = conv2bs(utmp[qq]);
        }
    }

    unsigned target = 8;

    for (int t = 0; t < TT; ++t) {
        const int t_in = dir ? (TT-1-t) : t;

        // ---- A: h from comm (t>0); u already staged last step ----
        if (t > 0) {
            for (int idx = tid; idx < 1024; idx += BLK) {
                int col = idx >> 2, q = idx & 3;
                u64 v = a_ldU(&cu[X_H + idx]);
                #pragma unroll
                for (int s = 0; s < 4; ++s)
                    sA[(4*q+s)*ASTR + DIN + col] = sel4(v, s);
            }
        }
        __syncthreads();

        // ---- B: fused G1(f/g/o strips, wv<6) + G2'(xz via Wcomb, all waves), K=KG ----
        {
            f4 accG = (f4){0.f,0.f,0.f,0.f};
            f4 accC = (f4){0.f,0.f,0.f,0.f};
            const int arow = lr*ASTR + lq*8;
            const short* browG = &Wg[(size_t)(wv < 6 ? n1 : 0)*KG + lq*8];
            const short* browC = &Wcb[(size_t)c1*KG + lq*8];
            #pragma unroll 4
            for (int k0 = 0; k0 < KG; k0 += 32) {
                bf8 a = *(const bf8*)&sA[arow + k0];
                if (wv < 6) {
                    bf8 bg = *(const bf8*)&browG[k0];
                    accG = MFMA16(a, bg, accG, 0, 0, 0);
                }
                bf8 bc = *(const bf8*)&browC[k0];
                accC = MFMA16(a, bc, accC, 0, 0, 0);
            }
            // G2' epilogue: conv+silu (xm) / silu (z); publish one u64 (4 rows) per lane
            float vv[4];
            #pragma unroll
            for (int jj = 0; jj < 4; ++jj) {
                float v = accC[jj];
                if (j < 4) v = fmaf(v, cw, cb);
                vv[jj] = v * sigmoidf_(v);
            }
            if (j < 4) a_stU(&cu[X_XM + c1*4 + lq], pack4(vv[0], vv[1], vv[2], vv[3]));
            else       a_stU(&cu[X_ZS + (c1-512)*4 + lq], pack4(vv[0], vv[1], vv[2], vv[3]));
            // G1 epilogue: activated gates into local LDS strips
            if (wv < 6) {
                #pragma unroll
                for (int jj = 0; jj < 4; ++jj) {
                    float v = accG[jj] + bs1;
                    int rr = lq*4 + jj;
                    if (q1 == 0)      sFs[rr*36 + kk1] = sigmoidf_(v);
                    else if (q1 == 1) sGs[rr*36 + kk1] = tanhf_(v);
                    else              sOs[rr*36 + kk1] = sigmoidf_(v);
                }
            }
        }
        gsync(cnt, target); target += 8;   // S_a: xm/zs exchanged

        // ---- C: stage full xm + zs (u64 loads) ----
        for (int idx = tid; idx < 2048; idx += BLK) {
            int col = idx >> 2, q = idx & 3;
            u64 ux = a_ldU(&cu[X_XM + idx]);
            u64 uz = a_ldU(&cu[X_ZS + idx]);
            #pragma unroll
            for (int s = 0; s < 4; ++s) {
                sXm[(4*q+s)*520 + col] = sel4(ux, s);
                sZs[(4*q+s)*520 + col] = sel4(uz, s);
            }
        }
        // prefetch u for t+1 (overlaps G3/phase4)
        if (t + 1 < TT) {
            const int tn = dir ? (TT-2-t) : (t+1);
            #pragma unroll
            for (int qq = 0; qq < NU; ++qq) {
                int idx = tid + qq*BLK;
                int r = idx / DIN, dd = idx % DIN;
                utmp[qq] = in[((size_t)(b0+r)*TT + tn)*DIN + dd];
            }
        }
        __syncthreads();

        // ---- D: G3 full (waves 0..2; LDS-cached Wxp) ----
        if (wv < 3) {
            f4 acc = (f4){0.f,0.f,0.f,0.f};
            const int arow = lr*520 + lq*8;
            const short* brow = &sWxp[(wv*16 + lr)*520 + lq*8];
            #pragma unroll 4
            for (int k0 = 0; k0 < 512; k0 += 32) {
                bf8 a = *(const bf8*)&sXm[arow + k0];
                bf8 b = *(const bf8*)&brow[k0];
                acc = MFMA16(a, b, acc, 0, 0, 0);
            }
            #pragma unroll
            for (int jj = 0; jj < 4; ++jj)
                sXd[(lq*4+jj)*52 + wv*16 + lr] = acc[jj];
        }
        __syncthreads();

        // ---- E: phase4 full-redundant — thread owns channel tid across 16 rows ----
        for (int r = 0; r < 16; ++r) {
            float dp = dtbv;
            #pragma unroll
            for (int p = 0; p < 16; ++p) dp = fmaf(sXd[r*52 + p], w16[p], dp);
            float bc = 0.f;
            #pragma unroll
            for (int s = 0; s < 16; ++s) bc = fmaf(sXd[r*52+16+s], sXd[r*52+32+s], bc);
            float xmv = bs2f(sXm[r*520 + tid]);
            float zsv = bs2f(sZs[r*520 + tid]);
            float yv = fmaf(softplusf_(dp), bc, Dmv) * xmv * zsv;
            sXm[r*520 + tid] = f2bs(yv);       // y in-place
        }
        __syncthreads();

        // ---- stage u(t+1) into sA now (uses the G4 window; off the post-sync path) ----
        if (t + 1 < TT) {
            #pragma unroll
            for (int qq = 0; qq < NU; ++qq) {
                int idx = tid + qq*BLK;
                int r = idx / DIN, dd = idx % DIN;
                sA[r*ASTR + dd] = conv2bs(utmp[qq]);
            }
        }

        // ---- F: G4 — own 32 cols (wv<2, LDS-cached Woutp); c/h update; publish h ----
        if (wv < 2) {
            f4 acc = (f4){0.f,0.f,0.f,0.f};
            const int arow = lr*520 + lq*8;
            const short* brow = &sWo[nloc*520 + lq*8];
            #pragma unroll 4
            for (int k0 = 0; k0 < 512; k0 += 32) {
                bf8 a = *(const bf8*)&sXm[arow + k0];
                bf8 b = *(const bf8*)&brow[k0];
                acc = MFMA16(a, b, acc, 0, 0, 0);
            }
            float hvv[4];
            #pragma unroll
            for (int jj = 0; jj < 4; ++jj) {
                int r = lq*4 + jj;
                float i_t = sigmoidf_(acc[jj] + bs4);
                float cv = fmaf(sFs[r*36 + nloc], sC[r*36 + nloc], i_t * sGs[r*36 + nloc]);
                sC[r*36 + nloc] = cv;
                float hv = sOs[r*36 + nloc] * tanhf_(cv);
                hvv[jj] = hv;
                storeval(&out[((size_t)(b0+r)*TT + t_in)*512 + (size_t)dir*256 + col4], hv);
            }
            a_stU(&cu[X_H + col4*4 + lq], pack4(hvv[0], hvv[1], hvv[2], hvv[3]));
        }
        gsync(cnt, target); target += 8;   // S_b: h exchanged
    }

    // ---- finals: own 32-col slice (h from comm, c from LDS) ----
    for (int idx = tid; idx < 16*32; idx += BLK) {
        int r = idx >> 5, kk = idx & 31;
        int col = 32*j + kk;
        u64 v = a_ldU(&cu[X_H + col*4 + (r >> 2)]);
        short s = sel4(v, r & 3);
        size_t dst = ((size_t)dir*BB + b0 + r)*256 + col;
        h_fin[dst] = bs2f(s);
        c_fin[dst] = sC[r*36 + kk];
    }
}

extern "C" void kernel_launch(void* const* d_in, const int* in_sizes, int n_in,
                              void* d_out, int out_size, void* d_ws, size_t ws_size,
                              hipStream_t stream)
{
    const float* x          = (const float*)d_in[0];
    const float* w_ih_l0    = (const float*)d_in[1];
    const float* w_hh_l0    = (const float*)d_in[2];
    const float* b_ih_l0    = (const float*)d_in[3];
    const float* b_hh_l0    = (const float*)d_in[4];
    const float* w_ih_l1    = (const float*)d_in[5];
    const float* w_hh_l1    = (const float*)d_in[6];
    const float* b_ih_l1    = (const float*)d_in[7];
    const float* b_hh_l1    = (const float*)d_in[8];
    const float* in_proj_w  = (const float*)d_in[9];
    const float* conv_w     = (const float*)d_in[10];
    const float* conv_b     = (const float*)d_in[11];
    const float* x_proj_w   = (const float*)d_in[12];
    const float* dt_proj_w  = (const float*)d_in[13];
    const float* dt_proj_b  = (const float*)d_in[14];
    const float* D_m        = (const float*)d_in[15];
    const float* out_proj_w = (const float*)d_in[16];

    short* wsu = (short*)d_ws;
    float* wsf = (float*)((char*)d_ws + FOFF);
    unsigned* cntAll = (unsigned*)(wsf + F_CNT);
    u64* commAll     = (u64*)(wsf + F_COMM);

    prep2<<<512, 256, 0, stream>>>(
        w_ih_l0, w_hh_l0, b_ih_l0, b_hh_l0,
        w_ih_l1, w_hh_l1, b_ih_l1, b_hh_l1,
        x_proj_w, out_proj_w, wsu, wsf);

    // Wcomb = in_proj_w @ Wcat_um (f32 accumulate, bf16 store)
    {
        dim3 g0(1024/16, 384/16, 2);
        wcomb_gemm<128><<<g0, 256, 0, stream>>>(in_proj_w, w_ih_l0, w_hh_l0, wsu + U_WCB0);
        dim3 g1(1024/16, 768/16, 2);
        wcomb_gemm<512><<<g1, 256, 0, stream>>>(in_proj_w, w_ih_l1, w_hh_l1, wsu + U_WCB1);
    }

    // layer 0: x fp32 (DIN=128) -> l0out bf16; finals -> H1/C1
    layer_coop<128, float, short><<<256, BLK, 0, stream>>>(
        x, wsu + U_L0,
        wsu + U_WC0, wsu + U_WCB0, wsu + U_XP, wsu + U_OUTP,
        wsf + F_BSUM0, conv_w, conv_b, dt_proj_w, dt_proj_b, D_m,
        wsf + F_H0, wsf + F_C0, wsf + F_H1, wsf + F_C1,
        commAll, cntAll, 0);

    // layer 1: l0out bf16 (DIN=512) -> d_out fp32; init from H1/C1
    layer_coop<512, short, float><<<256, BLK, 0, stream>>>(
        wsu + U_L0, (float*)d_out,
        wsu + U_WC1, wsu + U_WCB1, wsu + U_XP, wsu + U_OUTP,
        wsf + F_BSUM1, conv_w, conv_b, dt_proj_w, dt_proj_b, D_m,
        wsf + F_H1, wsf + F_C1, wsf + F_H0, wsf + F_C0,
        commAll, cntAll, 1);
}